// Round 3
// baseline (332.129 us; speedup 1.0000x reference)
//
#include <hip/hip_runtime.h>
#include <stdint.h>

#define B_ 8
#define K_ 8
#define N_ 128
#define D_ 256
#define H_ 128
#define NNEG_ 64

typedef unsigned long long u64;

// ---------------------------------------------------------------------------
// u64 wave shuffles (2x32-bit)
// ---------------------------------------------------------------------------
__device__ __forceinline__ u64 shfl_xor_u64(u64 v, int m) {
    int lo = __shfl_xor((int)(unsigned)v, m, 64);
    int hi = __shfl_xor((int)(unsigned)(v >> 32), m, 64);
    return ((u64)(unsigned)hi << 32) | (unsigned)lo;
}
__device__ __forceinline__ u64 shfl_u64(u64 v, int lane) {
    int lo = __shfl((int)(unsigned)v, lane, 64);
    int hi = __shfl((int)(unsigned)(v >> 32), lane, 64);
    return ((u64)(unsigned)hi << 32) | (unsigned)lo;
}

// full bitonic sort of 64 lanes, ascending across lane index
__device__ __forceinline__ u64 wave_sort64(u64 v, int lane) {
#pragma unroll
    for (int k = 2; k <= 64; k <<= 1) {
#pragma unroll
        for (int j = k >> 1; j > 0; j >>= 1) {
            u64 o = shfl_xor_u64(v, j);
            bool keepMin = (((lane & j) == 0) == ((lane & k) == 0));
            bool lt = v < o;
            v = (keepMin == lt) ? v : o;
        }
    }
    return v;
}
// cleanup merge of a bitonic 64-seq -> ascending
__device__ __forceinline__ u64 bitonic_merge64(u64 m, int lane) {
#pragma unroll
    for (int j = 32; j > 0; j >>= 1) {
        u64 o = shfl_xor_u64(m, j);
        bool keepMin = ((lane & j) == 0);
        bool lt = m < o;
        m = (keepMin == lt) ? m : o;
    }
    return m;
}

// ---------------------------------------------------------------------------
// Merged GEMMs + is_target: blocks 0..447 compute 4 projections
// (OUT[r,h] = sum_d A[r,d]*W[d,h]), blocks 448..451 write is_target.
// ---------------------------------------------------------------------------
__global__ __launch_bounds__(256) void gemm_all(
    const float* __restrict__ pos, const float* __restrict__ neg,
    const float* __restrict__ Wu1, const float* __restrict__ Wp1,
    const int* __restrict__ pos_classes, const int* __restrict__ target_class,
    float* __restrict__ HU0, float* __restrict__ HU1n,
    float* __restrict__ HP0, float* __restrict__ HP1,
    float* __restrict__ outp) {
    int bid = blockIdx.x;
    int t = threadIdx.x;
    if (bid >= 448) {
        int base = (bid - 448) * 2048 + t * 8;
#pragma unroll
        for (int q = 0; q < 8; ++q) {
            int idx = base + q;
            outp[64 + idx] = (pos_classes[idx] == target_class[idx >> 10]) ? 1.0f : 0.0f;
        }
        return;
    }
    const float* A; const float* W; float* OUT; int rb;
    if (bid < 128)      { A = pos; W = Wu1;           OUT = HU0;  rb = bid * 64; }
    else if (bid < 192) { A = neg; W = Wu1 + D_ * H_; OUT = HU1n; rb = (bid - 128) * 64; }
    else if (bid < 320) { A = pos; W = Wp1;           OUT = HP0;  rb = (bid - 192) * 64; }
    else                { A = pos; W = Wp1 + D_ * H_; OUT = HP1;  rb = (bid - 320) * 64; }

    __shared__ float As[64][17];
    __shared__ float Bs[16][128];
    int tx = t & 15, ty = t >> 4;
    float acc[4][8];
#pragma unroll
    for (int i = 0; i < 4; ++i)
#pragma unroll
        for (int j = 0; j < 8; ++j) acc[i][j] = 0.f;

    for (int k0 = 0; k0 < D_; k0 += 16) {
        {
            int row = t >> 2, kq = (t & 3) * 4;
            const float4 av = *(const float4*)&A[(size_t)(rb + row) * D_ + k0 + kq];
            As[row][kq + 0] = av.x; As[row][kq + 1] = av.y;
            As[row][kq + 2] = av.z; As[row][kq + 3] = av.w;
        }
        {
            int flat = t * 8;
            int kr = flat >> 7, hc = flat & 127;
            float4 b0 = *(const float4*)&W[(size_t)(k0 + kr) * H_ + hc];
            float4 b1 = *(const float4*)&W[(size_t)(k0 + kr) * H_ + hc + 4];
            *(float4*)&Bs[kr][hc] = b0;
            *(float4*)&Bs[kr][hc + 4] = b1;
        }
        __syncthreads();
#pragma unroll
        for (int kk = 0; kk < 16; ++kk) {
            float a0 = As[ty * 4 + 0][kk], a1 = As[ty * 4 + 1][kk];
            float a2 = As[ty * 4 + 2][kk], a3 = As[ty * 4 + 3][kk];
            float bv[8];
            *(float4*)&bv[0] = *(const float4*)&Bs[kk][tx * 8];
            *(float4*)&bv[4] = *(const float4*)&Bs[kk][tx * 8 + 4];
#pragma unroll
            for (int j = 0; j < 8; ++j) {
                acc[0][j] += a0 * bv[j];
                acc[1][j] += a1 * bv[j];
                acc[2][j] += a2 * bv[j];
                acc[3][j] += a3 * bv[j];
            }
        }
        __syncthreads();
    }
#pragma unroll
    for (int i = 0; i < 4; ++i) {
        float4 o0 = {acc[i][0], acc[i][1], acc[i][2], acc[i][3]};
        float4 o1 = {acc[i][4], acc[i][5], acc[i][6], acc[i][7]};
        *(float4*)&OUT[(size_t)(rb + ty * 4 + i) * H_ + tx * 8] = o0;
        *(float4*)&OUT[(size_t)(rb + ty * 4 + i) * H_ + tx * 8 + 4] = o1;
    }
}

// ---------------------------------------------------------------------------
// ue: t0[bk,m] = (1/64)*sum_n dot(relu(HU0[bk,m]+HU1n[bk,n]+bu1), wu2) + bu2
// grid (64, 4), block 256.
// ---------------------------------------------------------------------------
__global__ __launch_bounds__(256) void ue_kernel(const float* __restrict__ HU0,
                                                 const float* __restrict__ HU1n,
                                                 const float* __restrict__ bu1,
                                                 const float* __restrict__ Wu2,
                                                 const float* __restrict__ bu2v,
                                                 float* __restrict__ t0) {
    __shared__ float Ls[32][129];
    __shared__ float Rs[64][129];
    __shared__ float ws[128];
    __shared__ float red[32][33];
    int bk = blockIdx.x, mt = blockIdx.y;
    int t = threadIdx.x;
    for (int i = t; i < 64 * 128; i += 256) {
        int n = i >> 7, h = i & 127;
        Rs[n][h] = HU1n[(size_t)(bk * NNEG_ + n) * H_ + h];
    }
    for (int i = t; i < 32 * 128; i += 256) {
        int m = i >> 7, h = i & 127;
        Ls[m][h] = HU0[(size_t)(bk * N_ + mt * 32 + m) * H_ + h] + bu1[h];
    }
    if (t < 128) ws[t] = Wu2[t];
    __syncthreads();

    int tm = t & 7, tn = t >> 3;
    const float* l0 = &Ls[tm * 4 + 0][0];
    const float* l1 = &Ls[tm * 4 + 1][0];
    const float* l2 = &Ls[tm * 4 + 2][0];
    const float* l3 = &Ls[tm * 4 + 3][0];
    const float* r0 = &Rs[tn * 2 + 0][0];
    const float* r1 = &Rs[tn * 2 + 1][0];
    float a00 = 0.f, a01 = 0.f, a10 = 0.f, a11 = 0.f;
    float a20 = 0.f, a21 = 0.f, a30 = 0.f, a31 = 0.f;
#pragma unroll 4
    for (int h = 0; h < 128; ++h) {
        float w = ws[h];
        float b0 = r0[h], b1 = r1[h];
        float a0 = l0[h], a1 = l1[h], a2 = l2[h], a3 = l3[h];
        float v;
        v = a0 + b0; v = v > 0.f ? v : 0.f; a00 += v * w;
        v = a0 + b1; v = v > 0.f ? v : 0.f; a01 += v * w;
        v = a1 + b0; v = v > 0.f ? v : 0.f; a10 += v * w;
        v = a1 + b1; v = v > 0.f ? v : 0.f; a11 += v * w;
        v = a2 + b0; v = v > 0.f ? v : 0.f; a20 += v * w;
        v = a2 + b1; v = v > 0.f ? v : 0.f; a21 += v * w;
        v = a3 + b0; v = v > 0.f ? v : 0.f; a30 += v * w;
        v = a3 + b1; v = v > 0.f ? v : 0.f; a31 += v * w;
    }
    red[tm * 4 + 0][tn] = a00 + a01;
    red[tm * 4 + 1][tn] = a10 + a11;
    red[tm * 4 + 2][tn] = a20 + a21;
    red[tm * 4 + 3][tn] = a30 + a31;
    __syncthreads();
    if (t < 32) {
        float s = 0.f;
        for (int q = 0; q < 32; ++q) s += red[t][q];
        t0[bk * N_ + mt * 32 + t] = s * (1.0f / NNEG_) + bu2v[0];
    }
}

// ---------------------------------------------------------------------------
// score+total with fused gather:
// S==0: L row m = HP0g[b*Lbs + Loff + m*H], R row n = HP1g[b*Rbs + Roff + n*H]
// S>0 : L row m = mean_q HP0[(b*2S+q)*N*H + sub[(2b)*64+m][q]*H]  (R: c=1)
// total[b, m0*M+m1] = tL[m0] + tR[m1] - (dot(relu(L+R+bp1),wp2)+bp2)
// grid (Bn, M/32, M/64-tiles), block 256.
// ---------------------------------------------------------------------------
__global__ __launch_bounds__(256) void score_kernel(
    const float* __restrict__ HP0g, const float* __restrict__ HP1g,
    int Lbs, int Rbs, int Loff, int Roff,
    const int* __restrict__ sub_prev, int S,
    const float* __restrict__ tLp, int tLbs,
    const float* __restrict__ tRp, int tRbs,
    const float* __restrict__ bp1, const float* __restrict__ Wp2,
    const float* __restrict__ bp2, float* __restrict__ total, int M) {
    int b = blockIdx.x, m0t = blockIdx.y, m1t = blockIdx.z;
    __shared__ float Ls[32][129];
    __shared__ float Rs[64][129];
    __shared__ float ws[128];
    int t = threadIdx.x;
    if (S == 0) {
        const float* Lg = HP0g + (size_t)b * Lbs + Loff + m0t * 32 * H_;
        const float* Rg = HP1g + (size_t)b * Rbs + Roff + m1t * 64 * H_;
        for (int i = t; i < 64 * 128; i += 256) {
            int n = i >> 7, h = i & 127;
            Rs[n][h] = Rg[(size_t)n * H_ + h];
        }
        for (int i = t; i < 32 * 128; i += 256) {
            int m = i >> 7, h = i & 127;
            Ls[m][h] = Lg[(size_t)m * H_ + h] + bp1[h];
        }
    } else {
        float invS = 1.0f / (float)S;
        for (int i = t; i < 64 * 128; i += 256) {
            int n = i >> 7, h = i & 127;
            const int* sr = sub_prev + (size_t)((2 * b + 1) * 64 + m1t * 64 + n) * S;
            float s = 0.f;
            for (int q = 0; q < S; ++q)
                s += HP1g[(size_t)(b * 2 * S + S + q) * N_ * H_ + (size_t)sr[q] * H_ + h];
            Rs[n][h] = s * invS;
        }
        for (int i = t; i < 32 * 128; i += 256) {
            int m = i >> 7, h = i & 127;
            const int* sr = sub_prev + (size_t)((2 * b) * 64 + m0t * 32 + m) * S;
            float s = 0.f;
            for (int q = 0; q < S; ++q)
                s += HP0g[(size_t)(b * 2 * S + q) * N_ * H_ + (size_t)sr[q] * H_ + h];
            Ls[m][h] = s * invS + bp1[h];
        }
    }
    if (t < 128) ws[t] = Wp2[t];
    __syncthreads();

    int tm = t & 7, tn = t >> 3;
    const float* l0 = &Ls[tm * 4 + 0][0];
    const float* l1 = &Ls[tm * 4 + 1][0];
    const float* l2 = &Ls[tm * 4 + 2][0];
    const float* l3 = &Ls[tm * 4 + 3][0];
    const float* r0 = &Rs[tn * 2 + 0][0];
    const float* r1 = &Rs[tn * 2 + 1][0];
    float a00 = 0.f, a01 = 0.f, a10 = 0.f, a11 = 0.f;
    float a20 = 0.f, a21 = 0.f, a30 = 0.f, a31 = 0.f;
#pragma unroll 4
    for (int h = 0; h < 128; ++h) {
        float w = ws[h];
        float b0 = r0[h], b1 = r1[h];
        float a0 = l0[h], a1 = l1[h], a2 = l2[h], a3 = l3[h];
        float v;
        v = a0 + b0; v = v > 0.f ? v : 0.f; a00 += v * w;
        v = a0 + b1; v = v > 0.f ? v : 0.f; a01 += v * w;
        v = a1 + b0; v = v > 0.f ? v : 0.f; a10 += v * w;
        v = a1 + b1; v = v > 0.f ? v : 0.f; a11 += v * w;
        v = a2 + b0; v = v > 0.f ? v : 0.f; a20 += v * w;
        v = a2 + b1; v = v > 0.f ? v : 0.f; a21 += v * w;
        v = a3 + b0; v = v > 0.f ? v : 0.f; a30 += v * w;
        v = a3 + b1; v = v > 0.f ? v : 0.f; a31 += v * w;
    }
    float bp2v = bp2[0];
    const float* tL = tLp + (size_t)b * tLbs;
    const float* tR = tRp + (size_t)b * tRbs;
    float* orow = total + (size_t)b * M * M;
    float accs[4][2] = {{a00, a01}, {a10, a11}, {a20, a21}, {a30, a31}};
#pragma unroll
    for (int i = 0; i < 4; ++i) {
        int m0 = m0t * 32 + tm * 4 + i;
        float tl = tL[m0];
#pragma unroll
        for (int j = 0; j < 2; ++j) {
            int m1 = m1t * 64 + tn * 2 + j;
            orow[(size_t)m0 * M + m1] = tl + tR[m1] - (accs[i][j] + bp2v);
        }
    }
}

// ---------------------------------------------------------------------------
// Fused top-64 + select.  Exact jax.lax.top_k order (ascending, tie->lower
// idx) via unique u64 keys (sortable_f32<<32)|idx.  Per wave: streaming
// register top-64 with ballot skip; one barrier; wave 0 merges waves and
// runs the select epilogue.
// mode 0: write sub_new pairs (p0,p1) + t_new      (level 0)
// mode 1: gather subA rows (S=2) -> sub_new + t_new (level 1)
// mode 2: k=1, gather subB rows (S=4) -> out floats (level 2)
// grid (Bn), block 512 (L=16384) or 256 (L=4096).
// ---------------------------------------------------------------------------
__global__ __launch_bounds__(512) void topk_kernel(
    const float* __restrict__ total, int L, int logM, int mode,
    const int* __restrict__ sub_prev,
    int* __restrict__ sub_new, float* __restrict__ t_new,
    float* __restrict__ outp) {
    int b = blockIdx.x;
    const float* row = total + (size_t)b * L;
    int t = threadIdx.x, lane = t & 63, w = t >> 6;
    int nw = blockDim.x >> 6;
    int per = L / nw;
    int base = w * per;
    int C = per >> 6;

    u64 R = ~0ull;  // sentinel: +inf keys (real keys are always smaller)
    for (int c = 0; c < C; ++c) {
        int idx = base + c * 64 + lane;
        unsigned u = __float_as_uint(row[idx]);
        u = (u & 0x80000000u) ? ~u : (u | 0x80000000u);
        u64 key = ((u64)u << 32) | (unsigned)idx;
        u64 thr = shfl_u64(R, 63);  // current 64th smallest
        if (__ballot(key < thr)) {
            u64 s = wave_sort64(key, lane);
            u64 br = shfl_xor_u64(s, 63);  // s[63-lane]
            u64 m = R < br ? R : br;
            R = bitonic_merge64(m, lane);
        }
    }

    __shared__ u64 sR[8][64];
    sR[w][lane] = R;
    __syncthreads();
    if (w != 0) return;
    for (int p = 1; p < nw; ++p) {
        u64 br = sR[p][63 ^ lane];
        u64 m = R < br ? R : br;
        R = bitonic_merge64(m, lane);
    }
    // epilogue (wave 0): R[lane] = lane-th smallest key
    int j = (int)(R & 0xFFFFFFFFull);
    unsigned up = (unsigned)(R >> 32);
    unsigned ub = (up & 0x80000000u) ? (up & 0x7FFFFFFFu) : ~up;
    float val = __uint_as_float(ub);
    int p0 = j >> logM, p1 = j & ((1 << logM) - 1);
    if (mode == 0) {
        sub_new[(b * 64 + lane) * 2 + 0] = p0;
        sub_new[(b * 64 + lane) * 2 + 1] = p1;
        t_new[b * 64 + lane] = val;
    } else if (mode == 1) {
        const int* s0 = sub_prev + (size_t)((2 * b) * 64 + p0) * 2;
        const int* s1 = sub_prev + (size_t)((2 * b + 1) * 64 + p1) * 2;
        int* o = sub_new + (size_t)(b * 64 + lane) * 4;
        o[0] = s0[0]; o[1] = s0[1]; o[2] = s1[0]; o[3] = s1[1];
        t_new[b * 64 + lane] = val;
    } else {
        if (lane == 0) {
            const int* s0 = sub_prev + (size_t)((2 * b) * 64 + p0) * 4;
            const int* s1 = sub_prev + (size_t)((2 * b + 1) * 64 + p1) * 4;
#pragma unroll
            for (int q = 0; q < 4; ++q) {
                outp[b * 8 + q] = (float)s0[q];
                outp[b * 8 + 4 + q] = (float)s1[q];
            }
        }
    }
}

extern "C" void kernel_launch(void* const* d_in, const int* in_sizes, int n_in,
                              void* d_out, int out_size, void* d_ws, size_t ws_size,
                              hipStream_t stream) {
    const float* pos = (const float*)d_in[0];
    const float* neg = (const float*)d_in[1];
    const int* pos_classes = (const int*)d_in[2];
    const int* target_class = (const int*)d_in[3];
    const float* Wp1 = (const float*)d_in[4];
    const float* bp1 = (const float*)d_in[5];
    const float* Wp2 = (const float*)d_in[6];
    const float* bp2 = (const float*)d_in[7];
    const float* Wu1 = (const float*)d_in[8];
    const float* bu1 = (const float*)d_in[9];
    const float* Wu2 = (const float*)d_in[10];
    const float* bu2 = (const float*)d_in[11];

    float* wsf = (float*)d_ws;
    float* HU0 = wsf;                      // 8192*128
    float* HP0 = HU0 + 1048576;            // 8192*128
    float* HP1 = HP0 + 1048576;            // 8192*128
    float* HU1n = HP1 + 1048576;           // 4096*128
    float* t0 = HU1n + 524288;             // 8192
    float* total = t0 + 8192;              // 32*16384
    float* tA = total + 524288;            // 2048
    float* tB = tA + 2048;                 // 2048
    int* subA = (int*)(tB + 2048);         // 32*64*2
    int* subB = subA + 4096;               // 16*64*4
    float* outp = (float*)d_out;

    // 1) four GEMMs + is_target (independent work, one launch)
    gemm_all<<<452, 256, 0, stream>>>(pos, neg, Wu1, Wp1, pos_classes,
                                      target_class, HU0, HU1n, HP0, HP1, outp);

    // 2) unary energies (initial totals: pe=0, UNARY_SCALES all 1)
    ue_kernel<<<dim3(64, 4), 256, 0, stream>>>(HU0, HU1n, bu1, Wu2, bu2, t0);

    // 3) level 0: Bn=32, M=128, S=1 (identity subs)
    score_kernel<<<dim3(32, 4, 2), 256, 0, stream>>>(
        HP0, HP1, 2 * N_ * H_, 2 * N_ * H_, 0, N_ * H_, nullptr, 0,
        t0, 2 * N_, t0 + N_, 2 * N_, bp1, Wp2, bp2, total, 128);
    topk_kernel<<<32, 512, 0, stream>>>(total, 128 * 128, 7, 0, nullptr,
                                        subA, tA, nullptr);

    // 4) level 1: Bn=16, M=64, S=2 (gather fused into score staging)
    score_kernel<<<dim3(16, 2, 1), 256, 0, stream>>>(
        HP0, HP1, 0, 0, 0, 0, subA, 2,
        tA, 128, tA + 64, 128, bp1, Wp2, bp2, total, 64);
    topk_kernel<<<16, 256, 0, stream>>>(total, 64 * 64, 6, 1, subA,
                                        subB, tB, nullptr);

    // 5) level 2: Bn=8, M=64, S=4, topk=1 -> writes out[0:64]
    score_kernel<<<dim3(8, 2, 1), 256, 0, stream>>>(
        HP0, HP1, 0, 0, 0, 0, subB, 4,
        tB, 128, tB + 64, 128, bp1, Wp2, bp2, total, 64);
    topk_kernel<<<8, 256, 0, stream>>>(total, 64 * 64, 6, 2, subB,
                                       nullptr, nullptr, outp);
}

// Round 4
// 230.394 us; speedup vs baseline: 1.4416x; 1.4416x over previous
//
#include <hip/hip_runtime.h>
#include <stdint.h>

#define B_ 8
#define K_ 8
#define N_ 128
#define D_ 256
#define H_ 128
#define NNEG_ 64

typedef unsigned long long u64;

// ---------------------------------------------------------------------------
// u64 wave shuffles (2x32-bit)
// ---------------------------------------------------------------------------
__device__ __forceinline__ u64 shfl_xor_u64(u64 v, int m) {
    int lo = __shfl_xor((int)(unsigned)v, m, 64);
    int hi = __shfl_xor((int)(unsigned)(v >> 32), m, 64);
    return ((u64)(unsigned)hi << 32) | (unsigned)lo;
}
__device__ __forceinline__ u64 shfl_u64(u64 v, int lane) {
    int lo = __shfl((int)(unsigned)v, lane, 64);
    int hi = __shfl((int)(unsigned)(v >> 32), lane, 64);
    return ((u64)(unsigned)hi << 32) | (unsigned)lo;
}
// full bitonic sort of 64 lanes, ascending across lane index
__device__ __forceinline__ u64 wave_sort64(u64 v, int lane) {
#pragma unroll
    for (int k = 2; k <= 64; k <<= 1) {
#pragma unroll
        for (int j = k >> 1; j > 0; j >>= 1) {
            u64 o = shfl_xor_u64(v, j);
            bool keepMin = (((lane & j) == 0) == ((lane & k) == 0));
            bool lt = v < o;
            v = (keepMin == lt) ? v : o;
        }
    }
    return v;
}
// cleanup merge of a bitonic 64-seq -> ascending
__device__ __forceinline__ u64 bitonic_merge64(u64 m, int lane) {
#pragma unroll
    for (int j = 32; j > 0; j >>= 1) {
        u64 o = shfl_xor_u64(m, j);
        bool keepMin = ((lane & j) == 0);
        bool lt = m < o;
        m = (keepMin == lt) ? m : o;
    }
    return m;
}
__device__ __forceinline__ unsigned sortable(float f) {
    unsigned u = __float_as_uint(f);
    return (u & 0x80000000u) ? ~u : (u | 0x80000000u);
}

// ---------------------------------------------------------------------------
// g1: 4 GEMMs + is_target.  blocks 0..447 projections, 448..451 is_target.
// ---------------------------------------------------------------------------
__global__ __launch_bounds__(256) void g1_gemm(
    const float* __restrict__ pos, const float* __restrict__ neg,
    const float* __restrict__ Wu1, const float* __restrict__ Wp1,
    const int* __restrict__ pos_classes, const int* __restrict__ target_class,
    float* __restrict__ HU0, float* __restrict__ HU1n,
    float* __restrict__ HP0, float* __restrict__ HP1,
    float* __restrict__ outp) {
    int bid = blockIdx.x;
    int t = threadIdx.x;
    if (bid >= 448) {
        int base = (bid - 448) * 2048 + t * 8;
#pragma unroll
        for (int q = 0; q < 8; ++q) {
            int idx = base + q;
            outp[64 + idx] = (pos_classes[idx] == target_class[idx >> 10]) ? 1.0f : 0.0f;
        }
        return;
    }
    const float* A; const float* W; float* OUT; int rb;
    if (bid < 128)      { A = pos; W = Wu1;           OUT = HU0;  rb = bid * 64; }
    else if (bid < 192) { A = neg; W = Wu1 + D_ * H_; OUT = HU1n; rb = (bid - 128) * 64; }
    else if (bid < 320) { A = pos; W = Wp1;           OUT = HP0;  rb = (bid - 192) * 64; }
    else                { A = pos; W = Wp1 + D_ * H_; OUT = HP1;  rb = (bid - 320) * 64; }

    __shared__ float As[64][17];
    __shared__ float Bs[16][128];
    int tx = t & 15, ty = t >> 4;
    float acc[4][8];
#pragma unroll
    for (int i = 0; i < 4; ++i)
#pragma unroll
        for (int j = 0; j < 8; ++j) acc[i][j] = 0.f;

    for (int k0 = 0; k0 < D_; k0 += 16) {
        {
            int row = t >> 2, kq = (t & 3) * 4;
            const float4 av = *(const float4*)&A[(size_t)(rb + row) * D_ + k0 + kq];
            As[row][kq + 0] = av.x; As[row][kq + 1] = av.y;
            As[row][kq + 2] = av.z; As[row][kq + 3] = av.w;
        }
        {
            int flat = t * 8;
            int kr = flat >> 7, hc = flat & 127;
            float4 b0 = *(const float4*)&W[(size_t)(k0 + kr) * H_ + hc];
            float4 b1 = *(const float4*)&W[(size_t)(k0 + kr) * H_ + hc + 4];
            *(float4*)&Bs[kr][hc] = b0;
            *(float4*)&Bs[kr][hc + 4] = b1;
        }
        __syncthreads();
#pragma unroll
        for (int kk = 0; kk < 16; ++kk) {
            float a0 = As[ty * 4 + 0][kk], a1 = As[ty * 4 + 1][kk];
            float a2 = As[ty * 4 + 2][kk], a3 = As[ty * 4 + 3][kk];
            float bv[8];
            *(float4*)&bv[0] = *(const float4*)&Bs[kk][tx * 8];
            *(float4*)&bv[4] = *(const float4*)&Bs[kk][tx * 8 + 4];
#pragma unroll
            for (int j = 0; j < 8; ++j) {
                acc[0][j] += a0 * bv[j];
                acc[1][j] += a1 * bv[j];
                acc[2][j] += a2 * bv[j];
                acc[3][j] += a3 * bv[j];
            }
        }
        __syncthreads();
    }
#pragma unroll
    for (int i = 0; i < 4; ++i) {
        float4 o0 = {acc[i][0], acc[i][1], acc[i][2], acc[i][3]};
        float4 o1 = {acc[i][4], acc[i][5], acc[i][6], acc[i][7]};
        *(float4*)&OUT[(size_t)(rb + ty * 4 + i) * H_ + tx * 8] = o0;
        *(float4*)&OUT[(size_t)(rb + ty * 4 + i) * H_ + tx * 8 + 4] = o1;
    }
}

// ---------------------------------------------------------------------------
// g2: blocks 0..255 = ue (t0), blocks 256..511 = score0 (raw sc, no t terms).
// sc0[b*16384 + m0*128 + m1] = dot(relu(L+R+bp1), wp2) + bp2
// ---------------------------------------------------------------------------
__global__ __launch_bounds__(256) void g2_ue_sc0(
    const float* __restrict__ HU0, const float* __restrict__ HU1n,
    const float* __restrict__ bu1, const float* __restrict__ Wu2,
    const float* __restrict__ bu2v,
    const float* __restrict__ HP0, const float* __restrict__ HP1,
    const float* __restrict__ bp1, const float* __restrict__ Wp2,
    const float* __restrict__ bp2,
    float* __restrict__ t0, float* __restrict__ sc0) {
    __shared__ float smem[13568];  // 54272 B
    float (*Ls)[129] = (float(*)[129])smem;            // 32x129
    float (*Rs)[129] = (float(*)[129])(smem + 4128);   // 64x129
    float* wsv = smem + 4128 + 8256;                   // 128
    float (*red)[33] = (float(*)[33])(smem + 4128 + 8256 + 128);  // 32x33

    int bid = blockIdx.x;
    int t = threadIdx.x;
    bool is_ue = bid < 256;

    if (is_ue) {
        int bk = bid >> 2, mt = bid & 3;
        for (int i = t; i < 64 * 128; i += 256) {
            int n = i >> 7, h = i & 127;
            Rs[n][h] = HU1n[(size_t)(bk * NNEG_ + n) * H_ + h];
        }
        for (int i = t; i < 32 * 128; i += 256) {
            int m = i >> 7, h = i & 127;
            Ls[m][h] = HU0[(size_t)(bk * N_ + mt * 32 + m) * H_ + h] + bu1[h];
        }
        if (t < 128) wsv[t] = Wu2[t];
    } else {
        int bid2 = bid - 256;
        int b = bid2 >> 3, m0t = (bid2 >> 1) & 3, m1t = bid2 & 1;
        const float* Lg = HP0 + (size_t)b * 2 * N_ * H_ + m0t * 32 * H_;
        const float* Rg = HP1 + (size_t)b * 2 * N_ * H_ + N_ * H_ + m1t * 64 * H_;
        for (int i = t; i < 64 * 128; i += 256) {
            int n = i >> 7, h = i & 127;
            Rs[n][h] = Rg[(size_t)n * H_ + h];
        }
        for (int i = t; i < 32 * 128; i += 256) {
            int m = i >> 7, h = i & 127;
            Ls[m][h] = Lg[(size_t)m * H_ + h] + bp1[h];
        }
        if (t < 128) wsv[t] = Wp2[t];
    }
    __syncthreads();

    int tm = t & 7, tn = t >> 3;
    const float* l0 = &Ls[tm * 4 + 0][0];
    const float* l1 = &Ls[tm * 4 + 1][0];
    const float* l2 = &Ls[tm * 4 + 2][0];
    const float* l3 = &Ls[tm * 4 + 3][0];
    const float* r0 = &Rs[tn * 2 + 0][0];
    const float* r1 = &Rs[tn * 2 + 1][0];
    float a00 = 0.f, a01 = 0.f, a10 = 0.f, a11 = 0.f;
    float a20 = 0.f, a21 = 0.f, a30 = 0.f, a31 = 0.f;
#pragma unroll 4
    for (int h = 0; h < 128; ++h) {
        float w = wsv[h];
        float b0 = r0[h], b1 = r1[h];
        float a0 = l0[h], a1 = l1[h], a2 = l2[h], a3 = l3[h];
        float v;
        v = a0 + b0; v = v > 0.f ? v : 0.f; a00 += v * w;
        v = a0 + b1; v = v > 0.f ? v : 0.f; a01 += v * w;
        v = a1 + b0; v = v > 0.f ? v : 0.f; a10 += v * w;
        v = a1 + b1; v = v > 0.f ? v : 0.f; a11 += v * w;
        v = a2 + b0; v = v > 0.f ? v : 0.f; a20 += v * w;
        v = a2 + b1; v = v > 0.f ? v : 0.f; a21 += v * w;
        v = a3 + b0; v = v > 0.f ? v : 0.f; a30 += v * w;
        v = a3 + b1; v = v > 0.f ? v : 0.f; a31 += v * w;
    }

    if (is_ue) {
        int bk = bid >> 2, mt = bid & 3;
        red[tm * 4 + 0][tn] = a00 + a01;
        red[tm * 4 + 1][tn] = a10 + a11;
        red[tm * 4 + 2][tn] = a20 + a21;
        red[tm * 4 + 3][tn] = a30 + a31;
        __syncthreads();
        if (t < 32) {
            float s = 0.f;
            for (int q = 0; q < 32; ++q) s += red[t][q];
            t0[bk * N_ + mt * 32 + t] = s * (1.0f / NNEG_) + bu2v[0];
        }
    } else {
        int bid2 = bid - 256;
        int b = bid2 >> 3, m0t = (bid2 >> 1) & 3, m1t = bid2 & 1;
        float bp2v = bp2[0];
        float* orow = sc0 + (size_t)b * 16384;
        float accs[4][2] = {{a00, a01}, {a10, a11}, {a20, a21}, {a30, a31}};
#pragma unroll
        for (int i = 0; i < 4; ++i) {
            int m0 = m0t * 32 + tm * 4 + i;
#pragma unroll
            for (int j = 0; j < 2; ++j) {
                int m1 = m1t * 64 + tn * 2 + j;
                orow[m0 * 128 + m1] = accs[i][j] + bp2v;
            }
        }
    }
}

// ---------------------------------------------------------------------------
// g3: level-0 topk phase A.  512 blocks = 32 rows x 16 slices of 1024.
// value = (t0L[m0] + t0R[m1]) - sc0  (t0 fused here).  Per block: sorted
// top-64 of its slice -> topA[(r*16+s)*64 + lane]  (key = sortable<<32|idx).
// ---------------------------------------------------------------------------
__global__ __launch_bounds__(256) void g3_topkA(const float* __restrict__ sc0,
                                                const float* __restrict__ t0,
                                                u64* __restrict__ topA) {
    int bid = blockIdx.x;
    int r = bid >> 4, s = bid & 15;
    int t = threadIdx.x, lane = t & 63, w = t >> 6;
    __shared__ float tt[256];
    __shared__ u64 sR[4][64];
    tt[t] = t0[r * 256 + t];
    __syncthreads();
    const float* row = sc0 + (size_t)r * 16384 + s * 1024;
    u64 R = ~0ull;
    int base = w * 256;
    for (int c = 0; c < 4; ++c) {
        int li = base + c * 64 + lane;
        int idx = s * 1024 + li;
        float v = (tt[idx >> 7] + tt[128 + (idx & 127)]) - row[li];
        u64 key = ((u64)sortable(v) << 32) | (unsigned)idx;
        u64 thr = shfl_u64(R, 63);
        if (__ballot(key < thr)) {
            u64 srt = wave_sort64(key, lane);
            u64 br = shfl_xor_u64(srt, 63);
            u64 m = R < br ? R : br;
            R = bitonic_merge64(m, lane);
        }
    }
    sR[w][lane] = R;
    __syncthreads();
    if (w == 0) {
        for (int p = 1; p < 4; ++p) {
            u64 br = sR[p][63 ^ lane];
            u64 m = R < br ? R : br;
            R = bitonic_merge64(m, lane);
        }
        topA[(size_t)bid * 64 + lane] = R;
    }
}

// ---------------------------------------------------------------------------
// g4: fused tail.  8 blocks x 1024 threads; block b owns level-0 rows
// 4b..4b+3, level-1 units 2b,2b+1, level-2 unit b.
// Phases: T0 merge (topA -> tA/pA), S1 score (x2 units), topk1, S2, T2+out.
// ---------------------------------------------------------------------------
__global__ __launch_bounds__(1024) void g4_tail(
    const float* __restrict__ HP0, const float* __restrict__ HP1,
    const u64* __restrict__ topA,
    const float* __restrict__ bp1, const float* __restrict__ Wp2,
    const float* __restrict__ bp2,
    float* __restrict__ sc1, float* __restrict__ sc2,
    float* __restrict__ outp) {
    int b = blockIdx.x;
    int t = threadIdx.x, lane = t & 63, w = t >> 6;

    __shared__ float tA4[4][64];
    __shared__ short pA[4][64][2];
    __shared__ float tB2[2][64];
    __shared__ short subB[2][64][4];
    __shared__ float wsv[128];
    __shared__ float bps[128];
    __shared__ u64 sR[16][64];       // merge scratch
    __shared__ float Ls[64][129];    // score staging
    __shared__ float Rs[32][129];

    if (t < 128) { wsv[t] = Wp2[t]; bps[t] = bp1[t]; }
    float bp2v = bp2[0];

    // ---- T0: merge 16 sorted-64 slices per row (4 rows, 4 waves each) ----
    {
        int g = w >> 2, v = w & 3;
        int r = b * 4 + g;
        const u64* basep = topA + ((size_t)r * 16 + v * 4) * 64;
        u64 R = basep[lane];
        for (int c = 1; c < 4; ++c) {
            u64 ch = basep[c * 64 + (63 ^ lane)];
            u64 m = R < ch ? R : ch;
            R = bitonic_merge64(m, lane);
        }
        sR[w][lane] = R;
    }
    __syncthreads();
    if ((w & 3) == 0) {
        int g = w >> 2;
        u64 R = sR[w][lane];
        for (int p = 1; p < 4; ++p) {
            u64 br = sR[w + p][63 ^ lane];
            u64 m = R < br ? R : br;
            R = bitonic_merge64(m, lane);
        }
        int j = (int)(R & 0xFFFFFFFFull);
        unsigned up = (unsigned)(R >> 32);
        unsigned ub = (up & 0x80000000u) ? (up & 0x7FFFFFFFu) : ~up;
        tA4[g][lane] = __uint_as_float(ub);
        pA[g][lane][0] = (short)(j >> 7);
        pA[g][lane][1] = (short)(j & 127);
    }
    __syncthreads();

    // ---- S1: score level-1 units u=0,1 (S=2 gather fused) ----
    for (int u = 0; u < 2; ++u) {
        for (int i = t; i < 8192; i += 1024) {
            int m = i >> 7, h = i & 127;
            int l0 = pA[2 * u][m][0], l1 = pA[2 * u][m][1];
            float s = HP0[(size_t)(b * 8 + u * 4 + 0) * 16384 + l0 * 128 + h]
                    + HP0[(size_t)(b * 8 + u * 4 + 1) * 16384 + l1 * 128 + h];
            Ls[m][h] = s * 0.5f + bps[h];
        }
        for (int hf = 0; hf < 2; ++hf) {
            __syncthreads();
            for (int i = t; i < 4096; i += 1024) {
                int n = i >> 7, h = i & 127;
                int nn = hf * 32 + n;
                int r0 = pA[2 * u + 1][nn][0], r1 = pA[2 * u + 1][nn][1];
                float s = HP1[(size_t)(b * 8 + u * 4 + 2) * 16384 + r0 * 128 + h]
                        + HP1[(size_t)(b * 8 + u * 4 + 3) * 16384 + r1 * 128 + h];
                Rs[n][h] = s * 0.5f;
            }
            __syncthreads();
            int m0g = t & 31, n = t >> 5;
            const float* lp0 = &Ls[2 * m0g + 0][0];
            const float* lp1 = &Ls[2 * m0g + 1][0];
            const float* rp = &Rs[n][0];
            float acc0 = 0.f, acc1 = 0.f;
#pragma unroll 4
            for (int h = 0; h < 128; ++h) {
                float wv = wsv[h], rv = rp[h];
                float v0 = lp0[h] + rv; v0 = v0 > 0.f ? v0 : 0.f; acc0 += v0 * wv;
                float v1 = lp1[h] + rv; v1 = v1 > 0.f ? v1 : 0.f; acc1 += v1 * wv;
            }
            float* o = sc1 + (size_t)(b * 2 + u) * 4096;
            o[(2 * m0g + 0) * 64 + hf * 32 + n] = acc0 + bp2v;
            o[(2 * m0g + 1) * 64 + hf * 32 + n] = acc1 + bp2v;
        }
        __syncthreads();
    }

    // ---- topk1: both units concurrently (8 waves each), L=4096 ----
    {
        int u = w >> 3, v = w & 7;
        const float* srow = sc1 + (size_t)(b * 2 + u) * 4096;
        u64 R = ~0ull;
        for (int c = 0; c < 8; ++c) {
            int idx = v * 512 + c * 64 + lane;
            float val = (tA4[2 * u][idx >> 6] + tA4[2 * u + 1][idx & 63]) - srow[idx];
            u64 key = ((u64)sortable(val) << 32) | (unsigned)idx;
            u64 thr = shfl_u64(R, 63);
            if (__ballot(key < thr)) {
                u64 srt = wave_sort64(key, lane);
                u64 br = shfl_xor_u64(srt, 63);
                u64 m = R < br ? R : br;
                R = bitonic_merge64(m, lane);
            }
        }
        sR[w][lane] = R;
    }
    __syncthreads();
    if ((w & 7) == 0) {
        int u = w >> 3;
        u64 R = sR[w][lane];
        for (int p = 1; p < 8; ++p) {
            u64 br = sR[w + p][63 ^ lane];
            u64 m = R < br ? R : br;
            R = bitonic_merge64(m, lane);
        }
        int j = (int)(R & 0xFFFFFFFFull);
        unsigned up = (unsigned)(R >> 32);
        unsigned ub = (up & 0x80000000u) ? (up & 0x7FFFFFFFu) : ~up;
        int p0 = j >> 6, p1 = j & 63;
        tB2[u][lane] = __uint_as_float(ub);
        subB[u][lane][0] = pA[2 * u][p0][0];
        subB[u][lane][1] = pA[2 * u][p0][1];
        subB[u][lane][2] = pA[2 * u + 1][p1][0];
        subB[u][lane][3] = pA[2 * u + 1][p1][1];
    }
    __syncthreads();

    // ---- S2: score level-2 (S=4 gather fused) ----
    {
        for (int i = t; i < 8192; i += 1024) {
            int m = i >> 7, h = i & 127;
            float s = 0.f;
#pragma unroll
            for (int q = 0; q < 4; ++q)
                s += HP0[(size_t)(b * 8 + q) * 16384 + subB[0][m][q] * 128 + h];
            Ls[m][h] = s * 0.25f + bps[h];
        }
        for (int hf = 0; hf < 2; ++hf) {
            __syncthreads();
            for (int i = t; i < 4096; i += 1024) {
                int n = i >> 7, h = i & 127;
                int nn = hf * 32 + n;
                float s = 0.f;
#pragma unroll
                for (int q = 0; q < 4; ++q)
                    s += HP1[(size_t)(b * 8 + 4 + q) * 16384 + subB[1][nn][q] * 128 + h];
                Rs[n][h] = s * 0.25f;
            }
            __syncthreads();
            int m0g = t & 31, n = t >> 5;
            const float* lp0 = &Ls[2 * m0g + 0][0];
            const float* lp1 = &Ls[2 * m0g + 1][0];
            const float* rp = &Rs[n][0];
            float acc0 = 0.f, acc1 = 0.f;
#pragma unroll 4
            for (int h = 0; h < 128; ++h) {
                float wv = wsv[h], rv = rp[h];
                float v0 = lp0[h] + rv; v0 = v0 > 0.f ? v0 : 0.f; acc0 += v0 * wv;
                float v1 = lp1[h] + rv; v1 = v1 > 0.f ? v1 : 0.f; acc1 += v1 * wv;
            }
            float* o = sc2 + (size_t)b * 4096;
            o[(2 * m0g + 0) * 64 + hf * 32 + n] = acc0 + bp2v;
            o[(2 * m0g + 1) * 64 + hf * 32 + n] = acc1 + bp2v;
        }
        __syncthreads();
    }

    // ---- T2: argmin of 4096 (k=1), write final output ----
    {
        const float* srow = sc2 + (size_t)b * 4096;
        u64 best = ~0ull;
        for (int c = 0; c < 4; ++c) {
            int idx = w * 256 + c * 64 + lane;
            float val = (tB2[0][idx >> 6] + tB2[1][idx & 63]) - srow[idx];
            u64 key = ((u64)sortable(val) << 32) | (unsigned)idx;
            best = key < best ? key : best;
        }
#pragma unroll
        for (int off = 32; off > 0; off >>= 1) {
            u64 o = shfl_xor_u64(best, off);
            best = o < best ? o : best;
        }
        if (lane == 0) sR[0][w] = best;
    }
    __syncthreads();
    if (t == 0) {
        u64 best = sR[0][0];
        for (int p = 1; p < 16; ++p) {
            u64 o = sR[0][p];
            best = o < best ? o : best;
        }
        int j = (int)(best & 0xFFFFFFFFull);
        int p0 = j >> 6, p1 = j & 63;
#pragma unroll
        for (int q = 0; q < 4; ++q) {
            outp[b * 8 + q] = (float)subB[0][p0][q];
            outp[b * 8 + 4 + q] = (float)subB[1][p1][q];
        }
    }
}

extern "C" void kernel_launch(void* const* d_in, const int* in_sizes, int n_in,
                              void* d_out, int out_size, void* d_ws, size_t ws_size,
                              hipStream_t stream) {
    const float* pos = (const float*)d_in[0];
    const float* neg = (const float*)d_in[1];
    const int* pos_classes = (const int*)d_in[2];
    const int* target_class = (const int*)d_in[3];
    const float* Wp1 = (const float*)d_in[4];
    const float* bp1 = (const float*)d_in[5];
    const float* Wp2 = (const float*)d_in[6];
    const float* bp2 = (const float*)d_in[7];
    const float* Wu1 = (const float*)d_in[8];
    const float* bu1 = (const float*)d_in[9];
    const float* Wu2 = (const float*)d_in[10];
    const float* bu2 = (const float*)d_in[11];

    float* wsf = (float*)d_ws;
    float* HU0 = wsf;                       // 1048576
    float* HP0 = HU0 + 1048576;             // 1048576
    float* HP1 = HP0 + 1048576;             // 1048576
    float* HU1n = HP1 + 1048576;            // 524288
    float* t0 = HU1n + 524288;              // 8192
    float* sc0 = t0 + 8192;                 // 524288 (reused as sc1/sc2 later)
    float* sc1 = sc0;                       // 16*4096 (after g3 consumed sc0)
    float* sc2 = sc1 + 65536;               // 8*4096
    u64* topA = (u64*)(sc0 + 524288);       // 32*16*64 u64
    float* outp = (float*)d_out;

    // 1) four GEMMs + is_target
    g1_gemm<<<452, 256, 0, stream>>>(pos, neg, Wu1, Wp1, pos_classes,
                                     target_class, HU0, HU1n, HP0, HP1, outp);
    // 2) ue (t0) + score0 (raw sc0) in one launch (independent given g1)
    g2_ue_sc0<<<512, 256, 0, stream>>>(HU0, HU1n, bu1, Wu2, bu2,
                                       HP0, HP1, bp1, Wp2, bp2, t0, sc0);
    // 3) level-0 topk phase A (t0 fused into reads)
    g3_topkA<<<512, 256, 0, stream>>>(sc0, t0, topA);
    // 4) fused tail: T0-merge + score1 + topk1 + score2 + topk2 + output
    g4_tail<<<8, 1024, 0, stream>>>(HP0, HP1, topA, bp1, Wp2, bp2,
                                    sc1, sc2, outp);
}

// Round 6
// 209.920 us; speedup vs baseline: 1.5822x; 1.0975x over previous
//
#include <hip/hip_runtime.h>
#include <stdint.h>

#define B_ 8
#define K_ 8
#define N_ 128
#define D_ 256
#define H_ 128
#define NNEG_ 64

typedef unsigned long long u64;

// ---------------------------------------------------------------------------
// u64 wave shuffles + bitonic helpers
// ---------------------------------------------------------------------------
__device__ __forceinline__ u64 shfl_xor_u64(u64 v, int m) {
    int lo = __shfl_xor((int)(unsigned)v, m, 64);
    int hi = __shfl_xor((int)(unsigned)(v >> 32), m, 64);
    return ((u64)(unsigned)hi << 32) | (unsigned)lo;
}
// cleanup merge of a bitonic 64-seq -> ascending across lanes
__device__ __forceinline__ u64 bitonic_merge64(u64 m, int lane) {
#pragma unroll
    for (int j = 32; j > 0; j >>= 1) {
        u64 o = shfl_xor_u64(m, j);
        bool keepMin = ((lane & j) == 0);
        bool lt = m < o;
        m = (keepMin == lt) ? m : o;
    }
    return m;
}
__device__ __forceinline__ unsigned sortable(float f) {
    unsigned u = __float_as_uint(f);
    return (u & 0x80000000u) ? ~u : (u | 0x80000000u);
}
__device__ __forceinline__ float unsortable(unsigned u) {
    return __uint_as_float((u & 0x80000000u) ? (u & 0x7FFFFFFFu) : ~u);
}
// wave0-only: sort cand[0..127] (cc valid, rest ignored) ascending; 2 elems/lane
__device__ __forceinline__ void sort128_wave0(u64* cand, int cc, int lane) {
    u64 v0 = (lane < cc) ? cand[lane] : ~0ull;
    u64 v1 = (64 + lane < cc) ? cand[64 + lane] : ~0ull;
#pragma unroll
    for (int k = 2; k <= 64; k <<= 1) {
        bool d0 = ((lane & k) == 0);
        bool d1 = (k == 64) ? false : d0;
#pragma unroll
        for (int j = k >> 1; j > 0; j >>= 1) {
            u64 o0 = shfl_xor_u64(v0, j);
            bool km0 = (((lane & j) == 0) == d0);
            v0 = (km0 == (v0 < o0)) ? v0 : o0;
            u64 o1 = shfl_xor_u64(v1, j);
            bool km1 = (((lane & j) == 0) == d1);
            v1 = (km1 == (v1 < o1)) ? v1 : o1;
        }
    }
    if (v0 > v1) { u64 tmp = v0; v0 = v1; v1 = tmp; }
#pragma unroll
    for (int j = 32; j > 0; j >>= 1) {
        bool km = ((lane & j) == 0);
        u64 o0 = shfl_xor_u64(v0, j);
        v0 = (km == (v0 < o0)) ? v0 : o0;
        u64 o1 = shfl_xor_u64(v1, j);
        v1 = (km == (v1 < o1)) ? v1 : o1;
    }
    cand[lane] = v0; cand[64 + lane] = v1;
}

// ---------------------------------------------------------------------------
// g1: 4 GEMMs + is_target.  blocks 0..447 projections, 448..451 is_target.
// ---------------------------------------------------------------------------
__global__ __launch_bounds__(256) void g1_gemm(
    const float* __restrict__ pos, const float* __restrict__ neg,
    const float* __restrict__ Wu1, const float* __restrict__ Wp1,
    const int* __restrict__ pos_classes, const int* __restrict__ target_class,
    float* __restrict__ HU0, float* __restrict__ HU1n,
    float* __restrict__ HP0, float* __restrict__ HP1,
    float* __restrict__ outp) {
    int bid = blockIdx.x;
    int t = threadIdx.x;
    if (bid >= 448) {
        int base = (bid - 448) * 2048 + t * 8;
#pragma unroll
        for (int q = 0; q < 8; ++q) {
            int idx = base + q;
            outp[64 + idx] = (pos_classes[idx] == target_class[idx >> 10]) ? 1.0f : 0.0f;
        }
        return;
    }
    const float* A; const float* W; float* OUT; int rb;
    if (bid < 128)      { A = pos; W = Wu1;           OUT = HU0;  rb = bid * 64; }
    else if (bid < 192) { A = neg; W = Wu1 + D_ * H_; OUT = HU1n; rb = (bid - 128) * 64; }
    else if (bid < 320) { A = pos; W = Wp1;           OUT = HP0;  rb = (bid - 192) * 64; }
    else                { A = pos; W = Wp1 + D_ * H_; OUT = HP1;  rb = (bid - 320) * 64; }

    __shared__ float As[64][17];
    __shared__ float Bs[16][128];
    int tx = t & 15, ty = t >> 4;
    float acc[4][8];
#pragma unroll
    for (int i = 0; i < 4; ++i)
#pragma unroll
        for (int j = 0; j < 8; ++j) acc[i][j] = 0.f;

    for (int k0 = 0; k0 < D_; k0 += 16) {
        {
            int row = t >> 2, kq = (t & 3) * 4;
            const float4 av = *(const float4*)&A[(size_t)(rb + row) * D_ + k0 + kq];
            As[row][kq + 0] = av.x; As[row][kq + 1] = av.y;
            As[row][kq + 2] = av.z; As[row][kq + 3] = av.w;
        }
        {
            int flat = t * 8;
            int kr = flat >> 7, hc = flat & 127;
            float4 b0 = *(const float4*)&W[(size_t)(k0 + kr) * H_ + hc];
            float4 b1 = *(const float4*)&W[(size_t)(k0 + kr) * H_ + hc + 4];
            *(float4*)&Bs[kr][hc] = b0;
            *(float4*)&Bs[kr][hc + 4] = b1;
        }
        __syncthreads();
#pragma unroll
        for (int kk = 0; kk < 16; ++kk) {
            float a0 = As[ty * 4 + 0][kk], a1 = As[ty * 4 + 1][kk];
            float a2 = As[ty * 4 + 2][kk], a3 = As[ty * 4 + 3][kk];
            float bv[8];
            *(float4*)&bv[0] = *(const float4*)&Bs[kk][tx * 8];
            *(float4*)&bv[4] = *(const float4*)&Bs[kk][tx * 8 + 4];
#pragma unroll
            for (int j = 0; j < 8; ++j) {
                acc[0][j] += a0 * bv[j];
                acc[1][j] += a1 * bv[j];
                acc[2][j] += a2 * bv[j];
                acc[3][j] += a3 * bv[j];
            }
        }
        __syncthreads();
    }
#pragma unroll
    for (int i = 0; i < 4; ++i) {
        float4 o0 = {acc[i][0], acc[i][1], acc[i][2], acc[i][3]};
        float4 o1 = {acc[i][4], acc[i][5], acc[i][6], acc[i][7]};
        *(float4*)&OUT[(size_t)(rb + ty * 4 + i) * H_ + tx * 8] = o0;
        *(float4*)&OUT[(size_t)(rb + ty * 4 + i) * H_ + tx * 8 + 4] = o1;
    }
}

// ---------------------------------------------------------------------------
// g2: blocks 0..255 = ue (t0), blocks 256..511 = score0 (sc0 = dot + bp2).
// ---------------------------------------------------------------------------
__global__ __launch_bounds__(256) void g2_ue_sc0(
    const float* __restrict__ HU0, const float* __restrict__ HU1n,
    const float* __restrict__ bu1, const float* __restrict__ Wu2,
    const float* __restrict__ bu2v,
    const float* __restrict__ HP0, const float* __restrict__ HP1,
    const float* __restrict__ bp1, const float* __restrict__ Wp2,
    const float* __restrict__ bp2,
    float* __restrict__ t0, float* __restrict__ sc0) {
    __shared__ float smem[13568];
    float (*Ls)[129] = (float(*)[129])smem;            // 32x129
    float (*Rs)[129] = (float(*)[129])(smem + 4128);   // 64x129
    float* wsv = smem + 4128 + 8256;                   // 128
    float (*red)[33] = (float(*)[33])(smem + 4128 + 8256 + 128);  // 32x33

    int bid = blockIdx.x;
    int t = threadIdx.x;
    bool is_ue = bid < 256;

    if (is_ue) {
        int bk = bid >> 2, mt = bid & 3;
        for (int i = t; i < 64 * 128; i += 256) {
            int n = i >> 7, h = i & 127;
            Rs[n][h] = HU1n[(size_t)(bk * NNEG_ + n) * H_ + h];
        }
        for (int i = t; i < 32 * 128; i += 256) {
            int m = i >> 7, h = i & 127;
            Ls[m][h] = HU0[(size_t)(bk * N_ + mt * 32 + m) * H_ + h] + bu1[h];
        }
        if (t < 128) wsv[t] = Wu2[t];
    } else {
        int bid2 = bid - 256;
        int b = bid2 >> 3, m0t = (bid2 >> 1) & 3, m1t = bid2 & 1;
        const float* Lg = HP0 + (size_t)b * 2 * N_ * H_ + m0t * 32 * H_;
        const float* Rg = HP1 + (size_t)b * 2 * N_ * H_ + N_ * H_ + m1t * 64 * H_;
        for (int i = t; i < 64 * 128; i += 256) {
            int n = i >> 7, h = i & 127;
            Rs[n][h] = Rg[(size_t)n * H_ + h];
        }
        for (int i = t; i < 32 * 128; i += 256) {
            int m = i >> 7, h = i & 127;
            Ls[m][h] = Lg[(size_t)m * H_ + h] + bp1[h];
        }
        if (t < 128) wsv[t] = Wp2[t];
    }
    __syncthreads();

    int tm = t & 7, tn = t >> 3;
    const float* l0 = &Ls[tm * 4 + 0][0];
    const float* l1 = &Ls[tm * 4 + 1][0];
    const float* l2 = &Ls[tm * 4 + 2][0];
    const float* l3 = &Ls[tm * 4 + 3][0];
    const float* r0 = &Rs[tn * 2 + 0][0];
    const float* r1 = &Rs[tn * 2 + 1][0];
    float a00 = 0.f, a01 = 0.f, a10 = 0.f, a11 = 0.f;
    float a20 = 0.f, a21 = 0.f, a30 = 0.f, a31 = 0.f;
#pragma unroll 4
    for (int h = 0; h < 128; ++h) {
        float w = wsv[h];
        float b0 = r0[h], b1 = r1[h];
        float a0 = l0[h], a1 = l1[h], a2 = l2[h], a3 = l3[h];
        float v;
        v = a0 + b0; v = v > 0.f ? v : 0.f; a00 += v * w;
        v = a0 + b1; v = v > 0.f ? v : 0.f; a01 += v * w;
        v = a1 + b0; v = v > 0.f ? v : 0.f; a10 += v * w;
        v = a1 + b1; v = v > 0.f ? v : 0.f; a11 += v * w;
        v = a2 + b0; v = v > 0.f ? v : 0.f; a20 += v * w;
        v = a2 + b1; v = v > 0.f ? v : 0.f; a21 += v * w;
        v = a3 + b0; v = v > 0.f ? v : 0.f; a30 += v * w;
        v = a3 + b1; v = v > 0.f ? v : 0.f; a31 += v * w;
    }

    if (is_ue) {
        int bk = bid >> 2, mt = bid & 3;
        red[tm * 4 + 0][tn] = a00 + a01;
        red[tm * 4 + 1][tn] = a10 + a11;
        red[tm * 4 + 2][tn] = a20 + a21;
        red[tm * 4 + 3][tn] = a30 + a31;
        __syncthreads();
        if (t < 32) {
            float s = 0.f;
            for (int q = 0; q < 32; ++q) s += red[t][q];
            t0[bk * N_ + mt * 32 + t] = s * (1.0f / NNEG_) + bu2v[0];
        }
    } else {
        int bid2 = bid - 256;
        int b = bid2 >> 3, m0t = (bid2 >> 1) & 3, m1t = bid2 & 1;
        float bp2v = bp2[0];
        float* orow = sc0 + (size_t)b * 16384;
        float accs[4][2] = {{a00, a01}, {a10, a11}, {a20, a21}, {a30, a31}};
#pragma unroll
        for (int i = 0; i < 4; ++i) {
            int m0 = m0t * 32 + tm * 4 + i;
#pragma unroll
            for (int j = 0; j < 2; ++j) {
                int m1 = m1t * 64 + tn * 2 + j;
                orow[m0 * 128 + m1] = accs[i][j] + bp2v;
            }
        }
    }
}

// ---------------------------------------------------------------------------
// g3: level-0 top-64 per row via 32-bit descent select.  32 blocks x 1024.
// val = t0L[m0] + t0R[m1] - sc0.  Output: tA[r][e] (float), pA[r][e]=(p0<<8)|p1.
// ---------------------------------------------------------------------------
__global__ __launch_bounds__(1024) void g3_top0(const float* __restrict__ sc0,
                                                const float* __restrict__ t0,
                                                float* __restrict__ tA,
                                                int* __restrict__ pA) {
    int r = blockIdx.x;
    int t = threadIdx.x, lane = t & 63, w = t >> 6;
    __shared__ float tt[256];
    __shared__ unsigned cntB[2][16];
    __shared__ unsigned Tsh[2];
    __shared__ unsigned ccnt;
    __shared__ u64 cand[128];
    if (t < 256) tt[t] = t0[r * 256 + t];
    if (t == 0) ccnt = 0u;
    __syncthreads();
    const float* row = sc0 + (size_t)r * 16384;
    unsigned sv[16];
#pragma unroll
    for (int j = 0; j < 16; ++j) {
        int idx = j * 1024 + t;
        float v = (tt[idx >> 7] + tt[128 + (idx & 127)]) - row[idx];
        sv[j] = sortable(v);
    }
    unsigned T = 0u;
    for (int bit = 31; bit >= 0; --bit) {
        unsigned C = T | (1u << bit);
        int c = 0;
#pragma unroll
        for (int j = 0; j < 16; ++j) c += (sv[j] < C) ? 1 : 0;
#pragma unroll
        for (int off = 32; off > 0; off >>= 1) c += __shfl_xor(c, off, 64);
        if (lane == 0) cntB[bit & 1][w] = (unsigned)c;
        __syncthreads();
        if (t == 0) {
            unsigned tot = 0;
            for (int p = 0; p < 16; ++p) tot += cntB[bit & 1][p];
            Tsh[bit & 1] = (tot < 64u) ? C : T;
        }
        __syncthreads();
        T = Tsh[bit & 1];
    }
#pragma unroll
    for (int j = 0; j < 16; ++j) {
        if (sv[j] <= T) {
            unsigned pos = atomicAdd(&ccnt, 1u);
            if (pos < 128u) {
                int idx = j * 1024 + t;
                cand[pos] = ((u64)sv[j] << 32) | (unsigned)idx;
            }
        }
    }
    __syncthreads();
    if (w == 0) {
        int cc = (int)(ccnt < 128u ? ccnt : 128u);
        sort128_wave0(cand, cc, lane);
        u64 kk = cand[lane];
        int idx = (int)(kk & 0xFFFFFFFFull);
        tA[r * 64 + lane] = unsortable((unsigned)(kk >> 32));
        pA[r * 64 + lane] = ((idx >> 7) << 8) | (idx & 127);
    }
}

// ---------------------------------------------------------------------------
// g4a: level-1 scoring + per-half top-64.  32 blocks (unit u, n-half) x 256.
// LsT/RsT transposed tiles, b128/b64 LDS reads; descent select; sorted-64 out.
// LsT needs 64 m-columns -> [68] padded (the round-5 [36] overflow was THE bug).
// ---------------------------------------------------------------------------
__global__ __launch_bounds__(256) void g4a_s1(
    const float* __restrict__ HP0, const float* __restrict__ HP1,
    const float* __restrict__ tA, const int* __restrict__ pA,
    const float* __restrict__ bp1, const float* __restrict__ Wp2,
    const float* __restrict__ bp2, u64* __restrict__ g4top) {
    int bid = blockIdx.x;
    int u = bid >> 1, half = bid & 1;
    int t = threadIdx.x, lane = t & 63, w = t >> 6;
    __shared__ float LsT[128][68];
    __shared__ float RsT[128][36];
    __shared__ float taL[64], taR[64];
    __shared__ int paL[64], paR[64];
    __shared__ float wsv[128];
    __shared__ unsigned cntB[2][4];
    __shared__ unsigned Tsh[2];
    __shared__ unsigned ccnt;
    __shared__ u64 cand[128];
    if (t < 64) { taL[t] = tA[(2 * u) * 64 + t]; paL[t] = pA[(2 * u) * 64 + t]; }
    else if (t < 128) { int e = t - 64; taR[e] = tA[(2 * u + 1) * 64 + e]; paR[e] = pA[(2 * u + 1) * 64 + e]; }
    if (t < 128) wsv[t] = Wp2[t];
    if (t == 0) ccnt = 0u;
    float bp2v = bp2[0];
    __syncthreads();
    // stage LsT (full 64 m) and RsT (this half's 32 n), S=2 means
    for (int i = t; i < 64 * 128; i += 256) {
        int m = i >> 7, h = i & 127;
        int pk = paL[m]; int a0 = pk >> 8, a1 = pk & 255;
        float s = HP0[(size_t)(4 * u) * 16384 + a0 * 128 + h]
                + HP0[(size_t)(4 * u + 1) * 16384 + a1 * 128 + h];
        LsT[h][m] = s * 0.5f + bp1[h];
    }
    for (int i = t; i < 32 * 128; i += 256) {
        int n = i >> 7, h = i & 127;
        int ng = half * 32 + n;
        int pk = paR[ng]; int c0 = pk >> 8, c1 = pk & 255;
        float s = HP1[(size_t)(4 * u + 2) * 16384 + c0 * 128 + h]
                + HP1[(size_t)(4 * u + 3) * 16384 + c1 * 128 + h];
        RsT[h][n] = s * 0.5f;
    }
    __syncthreads();
    int qm = w * 4 + (lane >> 4);   // [0,16): m = qm*4 + mi
    int qn = lane & 15;             // n_local = qn*2 + nj
    float acc[4][2];
#pragma unroll
    for (int i = 0; i < 4; ++i) { acc[i][0] = 0.f; acc[i][1] = 0.f; }
#pragma unroll 2
    for (int h = 0; h < 128; ++h) {
        float4 lv = *(const float4*)&LsT[h][qm * 4];
        float2 rv = *(const float2*)&RsT[h][qn * 2];
        float wv = wsv[h];
        float v;
        v = lv.x + rv.x; v = v > 0.f ? v : 0.f; acc[0][0] += v * wv;
        v = lv.x + rv.y; v = v > 0.f ? v : 0.f; acc[0][1] += v * wv;
        v = lv.y + rv.x; v = v > 0.f ? v : 0.f; acc[1][0] += v * wv;
        v = lv.y + rv.y; v = v > 0.f ? v : 0.f; acc[1][1] += v * wv;
        v = lv.z + rv.x; v = v > 0.f ? v : 0.f; acc[2][0] += v * wv;
        v = lv.z + rv.y; v = v > 0.f ? v : 0.f; acc[2][1] += v * wv;
        v = lv.w + rv.x; v = v > 0.f ? v : 0.f; acc[3][0] += v * wv;
        v = lv.w + rv.y; v = v > 0.f ? v : 0.f; acc[3][1] += v * wv;
    }
    unsigned sv[8];
#pragma unroll
    for (int mi = 0; mi < 4; ++mi) {
#pragma unroll
        for (int nj = 0; nj < 2; ++nj) {
            int m = qm * 4 + mi;
            int ng = half * 32 + qn * 2 + nj;
            float val = (taL[m] + taR[ng]) - (acc[mi][nj] + bp2v);
            sv[mi * 2 + nj] = sortable(val);
        }
    }
    unsigned T = 0u;
    for (int bit = 31; bit >= 0; --bit) {
        unsigned C = T | (1u << bit);
        int c = 0;
#pragma unroll
        for (int j = 0; j < 8; ++j) c += (sv[j] < C) ? 1 : 0;
#pragma unroll
        for (int off = 32; off > 0; off >>= 1) c += __shfl_xor(c, off, 64);
        if (lane == 0) cntB[bit & 1][w] = (unsigned)c;
        __syncthreads();
        if (t == 0) {
            unsigned tot = cntB[bit & 1][0] + cntB[bit & 1][1] + cntB[bit & 1][2] + cntB[bit & 1][3];
            Tsh[bit & 1] = (tot < 64u) ? C : T;
        }
        __syncthreads();
        T = Tsh[bit & 1];
    }
#pragma unroll
    for (int j = 0; j < 8; ++j) {
        if (sv[j] <= T) {
            unsigned pos = atomicAdd(&ccnt, 1u);
            if (pos < 128u) {
                int mi = j >> 1, nj = j & 1;
                int idx = (qm * 4 + mi) * 64 + half * 32 + qn * 2 + nj;
                cand[pos] = ((u64)sv[j] << 32) | (unsigned)idx;
            }
        }
    }
    __syncthreads();
    if (w == 0) {
        int cc = (int)(ccnt < 128u ? ccnt : 128u);
        sort128_wave0(cand, cc, lane);
        g4top[(size_t)bid * 64 + lane] = cand[lane];
    }
}

// ---------------------------------------------------------------------------
// g4b: merge half-topks -> level-1 top-64; level-2 scoring (S=4) + argmin; out.
// 8 blocks x 256.
// ---------------------------------------------------------------------------
__global__ __launch_bounds__(256) void g4b_s2(
    const float* __restrict__ HP0, const float* __restrict__ HP1,
    const int* __restrict__ pA, const u64* __restrict__ g4top,
    const float* __restrict__ bp1, const float* __restrict__ Wp2,
    const float* __restrict__ bp2, float* __restrict__ outp) {
    int b = blockIdx.x;
    int t = threadIdx.x, lane = t & 63, w = t >> 6;
    __shared__ float LsT[128][68];
    __shared__ float RsT[128][36];
    __shared__ float tL[64], tR[64];
    __shared__ unsigned subL[64], subR[64];
    __shared__ float wsv[128];
    __shared__ u64 sred[4];
    if (t < 128) wsv[t] = Wp2[t];
    float bp2v = bp2[0];
    // merge two sorted half-lists per unit; wave0 -> unit 2b (L), wave1 -> 2b+1 (R)
    if (w < 2) {
        const u64* A = g4top + (size_t)(4 * b + 2 * w) * 64;
        const u64* Bp = g4top + (size_t)(4 * b + 2 * w + 1) * 64;
        u64 x = A[lane], y = Bp[63 - lane];
        u64 m = x < y ? x : y;
        m = bitonic_merge64(m, lane);
        int idx = (int)(m & 0xFFFFFFFFull);
        int p0 = idx >> 6, p1 = idx & 63;
        float val = unsortable((unsigned)(m >> 32));
        int rowL = 4 * b + 2 * w;
        int pkL = pA[rowL * 64 + p0];
        int pkR = pA[(rowL + 1) * 64 + p1];
        unsigned leaves = ((unsigned)pkL << 16) | (unsigned)pkR;  // bytes: a0,a1,c0,c1
        if (w == 0) { tL[lane] = val; subL[lane] = leaves; }
        else        { tR[lane] = val; subR[lane] = leaves; }
    }
    __syncthreads();
    // stage LsT: S=4 means from HP0 bks 8b..8b+3
    for (int i = t; i < 64 * 128; i += 256) {
        int m = i >> 7, h = i & 127;
        unsigned s4 = subL[m];
        float s = HP0[(size_t)(8 * b + 0) * 16384 + ((s4 >> 24) & 255u) * 128 + h]
                + HP0[(size_t)(8 * b + 1) * 16384 + ((s4 >> 16) & 255u) * 128 + h]
                + HP0[(size_t)(8 * b + 2) * 16384 + ((s4 >> 8) & 255u) * 128 + h]
                + HP0[(size_t)(8 * b + 3) * 16384 + (s4 & 255u) * 128 + h];
        LsT[h][m] = s * 0.25f + bp1[h];
    }
    u64 best = ~0ull;
    int qm = w * 4 + (lane >> 4);
    int qn = lane & 15;
    for (int half = 0; half < 2; ++half) {
        __syncthreads();
        for (int i = t; i < 32 * 128; i += 256) {
            int n = i >> 7, h = i & 127;
            int ng = half * 32 + n;
            unsigned s4 = subR[ng];
            float s = HP1[(size_t)(8 * b + 4) * 16384 + ((s4 >> 24) & 255u) * 128 + h]
                    + HP1[(size_t)(8 * b + 5) * 16384 + ((s4 >> 16) & 255u) * 128 + h]
                    + HP1[(size_t)(8 * b + 6) * 16384 + ((s4 >> 8) & 255u) * 128 + h]
                    + HP1[(size_t)(8 * b + 7) * 16384 + (s4 & 255u) * 128 + h];
            RsT[h][n] = s * 0.25f;
        }
        __syncthreads();
        float acc[4][2];
#pragma unroll
        for (int i = 0; i < 4; ++i) { acc[i][0] = 0.f; acc[i][1] = 0.f; }
#pragma unroll 2
        for (int h = 0; h < 128; ++h) {
            float4 lv = *(const float4*)&LsT[h][qm * 4];
            float2 rv = *(const float2*)&RsT[h][qn * 2];
            float wv = wsv[h];
            float v;
            v = lv.x + rv.x; v = v > 0.f ? v : 0.f; acc[0][0] += v * wv;
            v = lv.x + rv.y; v = v > 0.f ? v : 0.f; acc[0][1] += v * wv;
            v = lv.y + rv.x; v = v > 0.f ? v : 0.f; acc[1][0] += v * wv;
            v = lv.y + rv.y; v = v > 0.f ? v : 0.f; acc[1][1] += v * wv;
            v = lv.z + rv.x; v = v > 0.f ? v : 0.f; acc[2][0] += v * wv;
            v = lv.z + rv.y; v = v > 0.f ? v : 0.f; acc[2][1] += v * wv;
            v = lv.w + rv.x; v = v > 0.f ? v : 0.f; acc[3][0] += v * wv;
            v = lv.w + rv.y; v = v > 0.f ? v : 0.f; acc[3][1] += v * wv;
        }
#pragma unroll
        for (int mi = 0; mi < 4; ++mi) {
#pragma unroll
            for (int nj = 0; nj < 2; ++nj) {
                int m = qm * 4 + mi;
                int ng = half * 32 + qn * 2 + nj;
                float val = (tL[m] + tR[ng]) - (acc[mi][nj] + bp2v);
                u64 kk = ((u64)sortable(val) << 32) | (unsigned)(m * 64 + ng);
                best = kk < best ? kk : best;
            }
        }
    }
#pragma unroll
    for (int off = 32; off > 0; off >>= 1) {
        u64 o = shfl_xor_u64(best, off);
        best = o < best ? o : best;
    }
    if (lane == 0) sred[w] = best;
    __syncthreads();
    if (t == 0) {
        u64 bb = sred[0];
        for (int p = 1; p < 4; ++p) { u64 o = sred[p]; bb = o < bb ? o : bb; }
        int idx = (int)(bb & 0xFFFFFFFFull);
        unsigned sl = subL[idx >> 6], sr = subR[idx & 63];
        outp[b * 8 + 0] = (float)((sl >> 24) & 255u);
        outp[b * 8 + 1] = (float)((sl >> 16) & 255u);
        outp[b * 8 + 2] = (float)((sl >> 8) & 255u);
        outp[b * 8 + 3] = (float)(sl & 255u);
        outp[b * 8 + 4] = (float)((sr >> 24) & 255u);
        outp[b * 8 + 5] = (float)((sr >> 16) & 255u);
        outp[b * 8 + 6] = (float)((sr >> 8) & 255u);
        outp[b * 8 + 7] = (float)(sr & 255u);
    }
}

extern "C" void kernel_launch(void* const* d_in, const int* in_sizes, int n_in,
                              void* d_out, int out_size, void* d_ws, size_t ws_size,
                              hipStream_t stream) {
    const float* pos = (const float*)d_in[0];
    const float* neg = (const float*)d_in[1];
    const int* pos_classes = (const int*)d_in[2];
    const int* target_class = (const int*)d_in[3];
    const float* Wp1 = (const float*)d_in[4];
    const float* bp1 = (const float*)d_in[5];
    const float* Wp2 = (const float*)d_in[6];
    const float* bp2 = (const float*)d_in[7];
    const float* Wu1 = (const float*)d_in[8];
    const float* bu1 = (const float*)d_in[9];
    const float* Wu2 = (const float*)d_in[10];
    const float* bu2 = (const float*)d_in[11];

    float* wsf = (float*)d_ws;
    float* HU0 = wsf;                       // 1048576
    float* HP0 = HU0 + 1048576;             // 1048576
    float* HP1 = HP0 + 1048576;             // 1048576
    float* HU1n = HP1 + 1048576;            // 524288
    float* t0 = HU1n + 524288;              // 8192
    float* sc0 = t0 + 8192;                 // 524288
    float* tA = sc0 + 524288;               // 2048
    int* pA = (int*)(tA + 2048);            // 2048
    u64* g4top = (u64*)(pA + 2048);         // 64*64 u64
    float* outp = (float*)d_out;

    g1_gemm<<<452, 256, 0, stream>>>(pos, neg, Wu1, Wp1, pos_classes,
                                     target_class, HU0, HU1n, HP0, HP1, outp);
    g2_ue_sc0<<<512, 256, 0, stream>>>(HU0, HU1n, bu1, Wu2, bu2,
                                       HP0, HP1, bp1, Wp2, bp2, t0, sc0);
    g3_top0<<<32, 1024, 0, stream>>>(sc0, t0, tA, pA);
    g4a_s1<<<32, 256, 0, stream>>>(HP0, HP1, tA, pA, bp1, Wp2, bp2, g4top);
    g4b_s2<<<8, 256, 0, stream>>>(HP0, HP1, pA, g4top, bp1, Wp2, bp2, outp);
}

// Round 7
// 207.892 us; speedup vs baseline: 1.5976x; 1.0098x over previous
//
#include <hip/hip_runtime.h>
#include <stdint.h>

#define B_ 8
#define K_ 8
#define N_ 128
#define D_ 256
#define H_ 128
#define NNEG_ 64

typedef unsigned long long u64;

// ---------------------------------------------------------------------------
// u64 wave shuffles + bitonic helpers
// ---------------------------------------------------------------------------
__device__ __forceinline__ u64 shfl_xor_u64(u64 v, int m) {
    int lo = __shfl_xor((int)(unsigned)v, m, 64);
    int hi = __shfl_xor((int)(unsigned)(v >> 32), m, 64);
    return ((u64)(unsigned)hi << 32) | (unsigned)lo;
}
// cleanup merge of a bitonic 64-seq -> ascending across lanes
__device__ __forceinline__ u64 bitonic_merge64(u64 m, int lane) {
#pragma unroll
    for (int j = 32; j > 0; j >>= 1) {
        u64 o = shfl_xor_u64(m, j);
        bool keepMin = ((lane & j) == 0);
        bool lt = m < o;
        m = (keepMin == lt) ? m : o;
    }
    return m;
}
__device__ __forceinline__ unsigned sortable(float f) {
    unsigned u = __float_as_uint(f);
    return (u & 0x80000000u) ? ~u : (u | 0x80000000u);
}
__device__ __forceinline__ float unsortable(unsigned u) {
    return __uint_as_float((u & 0x80000000u) ? (u & 0x7FFFFFFFu) : ~u);
}
// wave0-only: sort cand[0..127] (cc valid, rest ignored) ascending; 2 elems/lane
__device__ __forceinline__ void sort128_wave0(u64* cand, int cc, int lane) {
    u64 v0 = (lane < cc) ? cand[lane] : ~0ull;
    u64 v1 = (64 + lane < cc) ? cand[64 + lane] : ~0ull;
#pragma unroll
    for (int k = 2; k <= 64; k <<= 1) {
        bool d0 = ((lane & k) == 0);
        bool d1 = (k == 64) ? false : d0;
#pragma unroll
        for (int j = k >> 1; j > 0; j >>= 1) {
            u64 o0 = shfl_xor_u64(v0, j);
            bool km0 = (((lane & j) == 0) == d0);
            v0 = (km0 == (v0 < o0)) ? v0 : o0;
            u64 o1 = shfl_xor_u64(v1, j);
            bool km1 = (((lane & j) == 0) == d1);
            v1 = (km1 == (v1 < o1)) ? v1 : o1;
        }
    }
    if (v0 > v1) { u64 tmp = v0; v0 = v1; v1 = tmp; }
#pragma unroll
    for (int j = 32; j > 0; j >>= 1) {
        bool km = ((lane & j) == 0);
        u64 o0 = shfl_xor_u64(v0, j);
        v0 = (km == (v0 < o0)) ? v0 : o0;
        u64 o1 = shfl_xor_u64(v1, j);
        v1 = (km == (v1 < o1)) ? v1 : o1;
    }
    cand[lane] = v0; cand[64 + lane] = v1;
}

// ---------------------------------------------------------------------------
// g1: 4 GEMMs + is_target.  blocks 0..447 projections, 448..451 is_target.
// ---------------------------------------------------------------------------
__global__ __launch_bounds__(256) void g1_gemm(
    const float* __restrict__ pos, const float* __restrict__ neg,
    const float* __restrict__ Wu1, const float* __restrict__ Wp1,
    const int* __restrict__ pos_classes, const int* __restrict__ target_class,
    float* __restrict__ HU0, float* __restrict__ HU1n,
    float* __restrict__ HP0, float* __restrict__ HP1,
    float* __restrict__ outp) {
    int bid = blockIdx.x;
    int t = threadIdx.x;
    if (bid >= 448) {
        int base = (bid - 448) * 2048 + t * 8;
#pragma unroll
        for (int q = 0; q < 8; ++q) {
            int idx = base + q;
            outp[64 + idx] = (pos_classes[idx] == target_class[idx >> 10]) ? 1.0f : 0.0f;
        }
        return;
    }
    const float* A; const float* W; float* OUT; int rb;
    if (bid < 128)      { A = pos; W = Wu1;           OUT = HU0;  rb = bid * 64; }
    else if (bid < 192) { A = neg; W = Wu1 + D_ * H_; OUT = HU1n; rb = (bid - 128) * 64; }
    else if (bid < 320) { A = pos; W = Wp1;           OUT = HP0;  rb = (bid - 192) * 64; }
    else                { A = pos; W = Wp1 + D_ * H_; OUT = HP1;  rb = (bid - 320) * 64; }

    __shared__ float As[64][17];
    __shared__ float Bs[16][128];
    int tx = t & 15, ty = t >> 4;
    float acc[4][8];
#pragma unroll
    for (int i = 0; i < 4; ++i)
#pragma unroll
        for (int j = 0; j < 8; ++j) acc[i][j] = 0.f;

    for (int k0 = 0; k0 < D_; k0 += 16) {
        {
            int row = t >> 2, kq = (t & 3) * 4;
            const float4 av = *(const float4*)&A[(size_t)(rb + row) * D_ + k0 + kq];
            As[row][kq + 0] = av.x; As[row][kq + 1] = av.y;
            As[row][kq + 2] = av.z; As[row][kq + 3] = av.w;
        }
        {
            int flat = t * 8;
            int kr = flat >> 7, hc = flat & 127;
            float4 b0 = *(const float4*)&W[(size_t)(k0 + kr) * H_ + hc];
            float4 b1 = *(const float4*)&W[(size_t)(k0 + kr) * H_ + hc + 4];
            *(float4*)&Bs[kr][hc] = b0;
            *(float4*)&Bs[kr][hc + 4] = b1;
        }
        __syncthreads();
#pragma unroll
        for (int kk = 0; kk < 16; ++kk) {
            float a0 = As[ty * 4 + 0][kk], a1 = As[ty * 4 + 1][kk];
            float a2 = As[ty * 4 + 2][kk], a3 = As[ty * 4 + 3][kk];
            float bv[8];
            *(float4*)&bv[0] = *(const float4*)&Bs[kk][tx * 8];
            *(float4*)&bv[4] = *(const float4*)&Bs[kk][tx * 8 + 4];
#pragma unroll
            for (int j = 0; j < 8; ++j) {
                acc[0][j] += a0 * bv[j];
                acc[1][j] += a1 * bv[j];
                acc[2][j] += a2 * bv[j];
                acc[3][j] += a3 * bv[j];
            }
        }
        __syncthreads();
    }
#pragma unroll
    for (int i = 0; i < 4; ++i) {
        float4 o0 = {acc[i][0], acc[i][1], acc[i][2], acc[i][3]};
        float4 o1 = {acc[i][4], acc[i][5], acc[i][6], acc[i][7]};
        *(float4*)&OUT[(size_t)(rb + ty * 4 + i) * H_ + tx * 8] = o0;
        *(float4*)&OUT[(size_t)(rb + ty * 4 + i) * H_ + tx * 8 + 4] = o1;
    }
}

// ---------------------------------------------------------------------------
// g2: blocks 0..255 = ue (t0), blocks 256..511 = score0 (sc0 = dot + bp2).
// ---------------------------------------------------------------------------
__global__ __launch_bounds__(256) void g2_ue_sc0(
    const float* __restrict__ HU0, const float* __restrict__ HU1n,
    const float* __restrict__ bu1, const float* __restrict__ Wu2,
    const float* __restrict__ bu2v,
    const float* __restrict__ HP0, const float* __restrict__ HP1,
    const float* __restrict__ bp1, const float* __restrict__ Wp2,
    const float* __restrict__ bp2,
    float* __restrict__ t0, float* __restrict__ sc0) {
    __shared__ float smem[13568];
    float (*Ls)[129] = (float(*)[129])smem;            // 32x129
    float (*Rs)[129] = (float(*)[129])(smem + 4128);   // 64x129
    float* wsv = smem + 4128 + 8256;                   // 128
    float (*red)[33] = (float(*)[33])(smem + 4128 + 8256 + 128);  // 32x33

    int bid = blockIdx.x;
    int t = threadIdx.x;
    bool is_ue = bid < 256;

    if (is_ue) {
        int bk = bid >> 2, mt = bid & 3;
        for (int i = t; i < 64 * 128; i += 256) {
            int n = i >> 7, h = i & 127;
            Rs[n][h] = HU1n[(size_t)(bk * NNEG_ + n) * H_ + h];
        }
        for (int i = t; i < 32 * 128; i += 256) {
            int m = i >> 7, h = i & 127;
            Ls[m][h] = HU0[(size_t)(bk * N_ + mt * 32 + m) * H_ + h] + bu1[h];
        }
        if (t < 128) wsv[t] = Wu2[t];
    } else {
        int bid2 = bid - 256;
        int b = bid2 >> 3, m0t = (bid2 >> 1) & 3, m1t = bid2 & 1;
        const float* Lg = HP0 + (size_t)b * 2 * N_ * H_ + m0t * 32 * H_;
        const float* Rg = HP1 + (size_t)b * 2 * N_ * H_ + N_ * H_ + m1t * 64 * H_;
        for (int i = t; i < 64 * 128; i += 256) {
            int n = i >> 7, h = i & 127;
            Rs[n][h] = Rg[(size_t)n * H_ + h];
        }
        for (int i = t; i < 32 * 128; i += 256) {
            int m = i >> 7, h = i & 127;
            Ls[m][h] = Lg[(size_t)m * H_ + h] + bp1[h];
        }
        if (t < 128) wsv[t] = Wp2[t];
    }
    __syncthreads();

    int tm = t & 7, tn = t >> 3;
    const float* l0 = &Ls[tm * 4 + 0][0];
    const float* l1 = &Ls[tm * 4 + 1][0];
    const float* l2 = &Ls[tm * 4 + 2][0];
    const float* l3 = &Ls[tm * 4 + 3][0];
    const float* r0 = &Rs[tn * 2 + 0][0];
    const float* r1 = &Rs[tn * 2 + 1][0];
    float a00 = 0.f, a01 = 0.f, a10 = 0.f, a11 = 0.f;
    float a20 = 0.f, a21 = 0.f, a30 = 0.f, a31 = 0.f;
#pragma unroll 4
    for (int h = 0; h < 128; ++h) {
        float w = wsv[h];
        float b0 = r0[h], b1 = r1[h];
        float a0 = l0[h], a1 = l1[h], a2 = l2[h], a3 = l3[h];
        float v;
        v = a0 + b0; v = v > 0.f ? v : 0.f; a00 += v * w;
        v = a0 + b1; v = v > 0.f ? v : 0.f; a01 += v * w;
        v = a1 + b0; v = v > 0.f ? v : 0.f; a10 += v * w;
        v = a1 + b1; v = v > 0.f ? v : 0.f; a11 += v * w;
        v = a2 + b0; v = v > 0.f ? v : 0.f; a20 += v * w;
        v = a2 + b1; v = v > 0.f ? v : 0.f; a21 += v * w;
        v = a3 + b0; v = v > 0.f ? v : 0.f; a30 += v * w;
        v = a3 + b1; v = v > 0.f ? v : 0.f; a31 += v * w;
    }

    if (is_ue) {
        int bk = bid >> 2, mt = bid & 3;
        red[tm * 4 + 0][tn] = a00 + a01;
        red[tm * 4 + 1][tn] = a10 + a11;
        red[tm * 4 + 2][tn] = a20 + a21;
        red[tm * 4 + 3][tn] = a30 + a31;
        __syncthreads();
        if (t < 32) {
            float s = 0.f;
            for (int q = 0; q < 32; ++q) s += red[t][q];
            t0[bk * N_ + mt * 32 + t] = s * (1.0f / NNEG_) + bu2v[0];
        }
    } else {
        int bid2 = bid - 256;
        int b = bid2 >> 3, m0t = (bid2 >> 1) & 3, m1t = bid2 & 1;
        float bp2v = bp2[0];
        float* orow = sc0 + (size_t)b * 16384;
        float accs[4][2] = {{a00, a01}, {a10, a11}, {a20, a21}, {a30, a31}};
#pragma unroll
        for (int i = 0; i < 4; ++i) {
            int m0 = m0t * 32 + tm * 4 + i;
#pragma unroll
            for (int j = 0; j < 2; ++j) {
                int m1 = m1t * 64 + tn * 2 + j;
                orow[m0 * 128 + m1] = accs[i][j] + bp2v;
            }
        }
    }
}

// ---------------------------------------------------------------------------
// g3: level-0 top-64 per row.  32 blocks x 1024 (16 waves).
// 2-bit descent select: 16 iterations, ONE barrier each.  Counts for the 3
// candidate thresholds are wave-reduced in registers (c1,c3 packed 16:16),
// accumulated with 2 LDS atomics per wave, then read by all threads.
// T ends as the exact rank-63 sortable value.
// ---------------------------------------------------------------------------
__global__ __launch_bounds__(1024) void g3_top0(const float* __restrict__ sc0,
                                                const float* __restrict__ t0,
                                                float* __restrict__ tA,
                                                int* __restrict__ pA) {
    int r = blockIdx.x;
    int t = threadIdx.x, lane = t & 63;
    __shared__ float tt[256];
    __shared__ unsigned cnt[16][2];   // [iter][c13 packed, c2]
    __shared__ unsigned ccnt;
    __shared__ u64 cand[128];
    if (t < 256) tt[t] = t0[r * 256 + t];
    if (t < 32) cnt[t >> 1][t & 1] = 0u;
    if (t == 0) ccnt = 0u;
    __syncthreads();
    const float* row = sc0 + (size_t)r * 16384;
    unsigned sv[16];
#pragma unroll
    for (int j = 0; j < 16; ++j) {
        int idx = j * 1024 + t;
        float v = (tt[idx >> 7] + tt[128 + (idx & 127)]) - row[idx];
        sv[j] = sortable(v);
    }
    unsigned T = 0u;
#pragma unroll
    for (int it = 0; it < 16; ++it) {
        int p = 30 - 2 * it;
        unsigned C1 = T | (1u << p), C2 = T | (2u << p), C3 = T | (3u << p);
        unsigned c13 = 0u, c2 = 0u;
#pragma unroll
        for (int j = 0; j < 16; ++j) {
            c13 += (sv[j] < C1) ? 1u : 0u;
            c13 += (sv[j] < C3) ? 0x10000u : 0u;
            c2 += (sv[j] < C2) ? 1u : 0u;
        }
#pragma unroll
        for (int off = 32; off > 0; off >>= 1) {
            c13 += (unsigned)__shfl_xor((int)c13, off, 64);
            c2 += (unsigned)__shfl_xor((int)c2, off, 64);
        }
        if (lane == 0) { atomicAdd(&cnt[it][0], c13); atomicAdd(&cnt[it][1], c2); }
        __syncthreads();
        unsigned t13 = cnt[it][0], t2v = cnt[it][1];
        unsigned t1 = t13 & 0xFFFFu, t3 = t13 >> 16;
        unsigned k = (t3 < 64u) ? 3u : (t2v < 64u) ? 2u : (t1 < 64u) ? 1u : 0u;
        T |= (k << p);
    }
#pragma unroll
    for (int j = 0; j < 16; ++j) {
        if (sv[j] <= T) {
            unsigned pos = atomicAdd(&ccnt, 1u);
            if (pos < 128u) {
                int idx = j * 1024 + t;
                cand[pos] = ((u64)sv[j] << 32) | (unsigned)idx;
            }
        }
    }
    __syncthreads();
    if (t < 64) {
        int cc = (int)(ccnt < 128u ? ccnt : 128u);
        sort128_wave0(cand, cc, lane);
        u64 kk = cand[lane];
        int idx = (int)(kk & 0xFFFFFFFFull);
        tA[r * 64 + lane] = unsortable((unsigned)(kk >> 32));
        pA[r * 64 + lane] = ((idx >> 7) << 8) | (idx & 127);
    }
}

// ---------------------------------------------------------------------------
// g4a: level-1 scoring + per-half top-64.  32 blocks (unit u, n-half) x 256.
// Transposed tiles with b128/b64 reads; 2-bit 1-barrier descent select.
// ---------------------------------------------------------------------------
__global__ __launch_bounds__(256) void g4a_s1(
    const float* __restrict__ HP0, const float* __restrict__ HP1,
    const float* __restrict__ tA, const int* __restrict__ pA,
    const float* __restrict__ bp1, const float* __restrict__ Wp2,
    const float* __restrict__ bp2, u64* __restrict__ g4top) {
    int bid = blockIdx.x;
    int u = bid >> 1, half = bid & 1;
    int t = threadIdx.x, lane = t & 63, w = t >> 6;
    __shared__ float LsT[128][68];
    __shared__ float RsT[128][36];
    __shared__ float taL[64], taR[64];
    __shared__ int paL[64], paR[64];
    __shared__ float wsv[128];
    __shared__ unsigned cnt[16][2];
    __shared__ unsigned ccnt;
    __shared__ u64 cand[128];
    if (t < 64) { taL[t] = tA[(2 * u) * 64 + t]; paL[t] = pA[(2 * u) * 64 + t]; }
    else if (t < 128) { int e = t - 64; taR[e] = tA[(2 * u + 1) * 64 + e]; paR[e] = pA[(2 * u + 1) * 64 + e]; }
    if (t < 128) wsv[t] = Wp2[t];
    if (t < 32) cnt[t >> 1][t & 1] = 0u;
    if (t == 0) ccnt = 0u;
    float bp2v = bp2[0];
    __syncthreads();
    // stage LsT (full 64 m) and RsT (this half's 32 n), S=2 means
    for (int i = t; i < 64 * 128; i += 256) {
        int m = i >> 7, h = i & 127;
        int pk = paL[m]; int a0 = pk >> 8, a1 = pk & 255;
        float s = HP0[(size_t)(4 * u) * 16384 + a0 * 128 + h]
                + HP0[(size_t)(4 * u + 1) * 16384 + a1 * 128 + h];
        LsT[h][m] = s * 0.5f + bp1[h];
    }
    for (int i = t; i < 32 * 128; i += 256) {
        int n = i >> 7, h = i & 127;
        int ng = half * 32 + n;
        int pk = paR[ng]; int c0 = pk >> 8, c1 = pk & 255;
        float s = HP1[(size_t)(4 * u + 2) * 16384 + c0 * 128 + h]
                + HP1[(size_t)(4 * u + 3) * 16384 + c1 * 128 + h];
        RsT[h][n] = s * 0.5f;
    }
    __syncthreads();
    int qm = w * 4 + (lane >> 4);   // [0,16): m = qm*4 + mi
    int qn = lane & 15;             // n_local = qn*2 + nj
    float acc[4][2];
#pragma unroll
    for (int i = 0; i < 4; ++i) { acc[i][0] = 0.f; acc[i][1] = 0.f; }
#pragma unroll 2
    for (int h = 0; h < 128; ++h) {
        float4 lv = *(const float4*)&LsT[h][qm * 4];
        float2 rv = *(const float2*)&RsT[h][qn * 2];
        float wv = wsv[h];
        float v;
        v = lv.x + rv.x; v = v > 0.f ? v : 0.f; acc[0][0] += v * wv;
        v = lv.x + rv.y; v = v > 0.f ? v : 0.f; acc[0][1] += v * wv;
        v = lv.y + rv.x; v = v > 0.f ? v : 0.f; acc[1][0] += v * wv;
        v = lv.y + rv.y; v = v > 0.f ? v : 0.f; acc[1][1] += v * wv;
        v = lv.z + rv.x; v = v > 0.f ? v : 0.f; acc[2][0] += v * wv;
        v = lv.z + rv.y; v = v > 0.f ? v : 0.f; acc[2][1] += v * wv;
        v = lv.w + rv.x; v = v > 0.f ? v : 0.f; acc[3][0] += v * wv;
        v = lv.w + rv.y; v = v > 0.f ? v : 0.f; acc[3][1] += v * wv;
    }
    unsigned sv[8];
#pragma unroll
    for (int mi = 0; mi < 4; ++mi) {
#pragma unroll
        for (int nj = 0; nj < 2; ++nj) {
            int m = qm * 4 + mi;
            int ng = half * 32 + qn * 2 + nj;
            float val = (taL[m] + taR[ng]) - (acc[mi][nj] + bp2v);
            sv[mi * 2 + nj] = sortable(val);
        }
    }
    unsigned T = 0u;
#pragma unroll
    for (int it = 0; it < 16; ++it) {
        int p = 30 - 2 * it;
        unsigned C1 = T | (1u << p), C2 = T | (2u << p), C3 = T | (3u << p);
        unsigned c13 = 0u, c2 = 0u;
#pragma unroll
        for (int j = 0; j < 8; ++j) {
            c13 += (sv[j] < C1) ? 1u : 0u;
            c13 += (sv[j] < C3) ? 0x10000u : 0u;
            c2 += (sv[j] < C2) ? 1u : 0u;
        }
#pragma unroll
        for (int off = 32; off > 0; off >>= 1) {
            c13 += (unsigned)__shfl_xor((int)c13, off, 64);
            c2 += (unsigned)__shfl_xor((int)c2, off, 64);
        }
        if (lane == 0) { atomicAdd(&cnt[it][0], c13); atomicAdd(&cnt[it][1], c2); }
        __syncthreads();
        unsigned t13 = cnt[it][0], t2v = cnt[it][1];
        unsigned t1 = t13 & 0xFFFFu, t3 = t13 >> 16;
        unsigned k = (t3 < 64u) ? 3u : (t2v < 64u) ? 2u : (t1 < 64u) ? 1u : 0u;
        T |= (k << p);
    }
#pragma unroll
    for (int j = 0; j < 8; ++j) {
        if (sv[j] <= T) {
            unsigned pos = atomicAdd(&ccnt, 1u);
            if (pos < 128u) {
                int mi = j >> 1, nj = j & 1;
                int idx = (qm * 4 + mi) * 64 + half * 32 + qn * 2 + nj;
                cand[pos] = ((u64)sv[j] << 32) | (unsigned)idx;
            }
        }
    }
    __syncthreads();
    if (w == 0) {
        int cc = (int)(ccnt < 128u ? ccnt : 128u);
        sort128_wave0(cand, cc, lane);
        g4top[(size_t)bid * 64 + lane] = cand[lane];
    }
}

// ---------------------------------------------------------------------------
// g4b: merge half-topks -> level-1 top-64; level-2 scoring (S=4) + argmin; out.
// 8 blocks x 256.
// ---------------------------------------------------------------------------
__global__ __launch_bounds__(256) void g4b_s2(
    const float* __restrict__ HP0, const float* __restrict__ HP1,
    const int* __restrict__ pA, const u64* __restrict__ g4top,
    const float* __restrict__ bp1, const float* __restrict__ Wp2,
    const float* __restrict__ bp2, float* __restrict__ outp) {
    int b = blockIdx.x;
    int t = threadIdx.x, lane = t & 63, w = t >> 6;
    __shared__ float LsT[128][68];
    __shared__ float RsT[128][36];
    __shared__ float tL[64], tR[64];
    __shared__ unsigned subL[64], subR[64];
    __shared__ float wsv[128];
    __shared__ u64 sred[4];
    if (t < 128) wsv[t] = Wp2[t];
    float bp2v = bp2[0];
    // merge two sorted half-lists per unit; wave0 -> unit 2b (L), wave1 -> 2b+1 (R)
    if (w < 2) {
        const u64* A = g4top + (size_t)(4 * b + 2 * w) * 64;
        const u64* Bp = g4top + (size_t)(4 * b + 2 * w + 1) * 64;
        u64 x = A[lane], y = Bp[63 - lane];
        u64 m = x < y ? x : y;
        m = bitonic_merge64(m, lane);
        int idx = (int)(m & 0xFFFFFFFFull);
        int p0 = idx >> 6, p1 = idx & 63;
        float val = unsortable((unsigned)(m >> 32));
        int rowL = 4 * b + 2 * w;
        int pkL = pA[rowL * 64 + p0];
        int pkR = pA[(rowL + 1) * 64 + p1];
        unsigned leaves = ((unsigned)pkL << 16) | (unsigned)pkR;  // bytes: a0,a1,c0,c1
        if (w == 0) { tL[lane] = val; subL[lane] = leaves; }
        else        { tR[lane] = val; subR[lane] = leaves; }
    }
    __syncthreads();
    // stage LsT: S=4 means from HP0 bks 8b..8b+3
    for (int i = t; i < 64 * 128; i += 256) {
        int m = i >> 7, h = i & 127;
        unsigned s4 = subL[m];
        float s = HP0[(size_t)(8 * b + 0) * 16384 + ((s4 >> 24) & 255u) * 128 + h]
                + HP0[(size_t)(8 * b + 1) * 16384 + ((s4 >> 16) & 255u) * 128 + h]
                + HP0[(size_t)(8 * b + 2) * 16384 + ((s4 >> 8) & 255u) * 128 + h]
                + HP0[(size_t)(8 * b + 3) * 16384 + (s4 & 255u) * 128 + h];
        LsT[h][m] = s * 0.25f + bp1[h];
    }
    u64 best = ~0ull;
    int qm = w * 4 + (lane >> 4);
    int qn = lane & 15;
    for (int half = 0; half < 2; ++half) {
        __syncthreads();
        for (int i = t; i < 32 * 128; i += 256) {
            int n = i >> 7, h = i & 127;
            int ng = half * 32 + n;
            unsigned s4 = subR[ng];
            float s = HP1[(size_t)(8 * b + 4) * 16384 + ((s4 >> 24) & 255u) * 128 + h]
                    + HP1[(size_t)(8 * b + 5) * 16384 + ((s4 >> 16) & 255u) * 128 + h]
                    + HP1[(size_t)(8 * b + 6) * 16384 + ((s4 >> 8) & 255u) * 128 + h]
                    + HP1[(size_t)(8 * b + 7) * 16384 + (s4 & 255u) * 128 + h];
            RsT[h][n] = s * 0.25f;
        }
        __syncthreads();
        float acc[4][2];
#pragma unroll
        for (int i = 0; i < 4; ++i) { acc[i][0] = 0.f; acc[i][1] = 0.f; }
#pragma unroll 2
        for (int h = 0; h < 128; ++h) {
            float4 lv = *(const float4*)&LsT[h][qm * 4];
            float2 rv = *(const float2*)&RsT[h][qn * 2];
            float wv = wsv[h];
            float v;
            v = lv.x + rv.x; v = v > 0.f ? v : 0.f; acc[0][0] += v * wv;
            v = lv.x + rv.y; v = v > 0.f ? v : 0.f; acc[0][1] += v * wv;
            v = lv.y + rv.x; v = v > 0.f ? v : 0.f; acc[1][0] += v * wv;
            v = lv.y + rv.y; v = v > 0.f ? v : 0.f; acc[1][1] += v * wv;
            v = lv.z + rv.x; v = v > 0.f ? v : 0.f; acc[2][0] += v * wv;
            v = lv.z + rv.y; v = v > 0.f ? v : 0.f; acc[2][1] += v * wv;
            v = lv.w + rv.x; v = v > 0.f ? v : 0.f; acc[3][0] += v * wv;
            v = lv.w + rv.y; v = v > 0.f ? v : 0.f; acc[3][1] += v * wv;
        }
#pragma unroll
        for (int mi = 0; mi < 4; ++mi) {
#pragma unroll
            for (int nj = 0; nj < 2; ++nj) {
                int m = qm * 4 + mi;
                int ng = half * 32 + qn * 2 + nj;
                float val = (tL[m] + tR[ng]) - (acc[mi][nj] + bp2v);
                u64 kk = ((u64)sortable(val) << 32) | (unsigned)(m * 64 + ng);
                best = kk < best ? kk : best;
            }
        }
    }
#pragma unroll
    for (int off = 32; off > 0; off >>= 1) {
        u64 o = shfl_xor_u64(best, off);
        best = o < best ? o : best;
    }
    if (lane == 0) sred[w] = best;
    __syncthreads();
    if (t == 0) {
        u64 bb = sred[0];
        for (int p = 1; p < 4; ++p) { u64 o = sred[p]; bb = o < bb ? o : bb; }
        int idx = (int)(bb & 0xFFFFFFFFull);
        unsigned sl = subL[idx >> 6], sr = subR[idx & 63];
        outp[b * 8 + 0] = (float)((sl >> 24) & 255u);
        outp[b * 8 + 1] = (float)((sl >> 16) & 255u);
        outp[b * 8 + 2] = (float)((sl >> 8) & 255u);
        outp[b * 8 + 3] = (float)(sl & 255u);
        outp[b * 8 + 4] = (float)((sr >> 24) & 255u);
        outp[b * 8 + 5] = (float)((sr >> 16) & 255u);
        outp[b * 8 + 6] = (float)((sr >> 8) & 255u);
        outp[b * 8 + 7] = (float)(sr & 255u);
    }
}

extern "C" void kernel_launch(void* const* d_in, const int* in_sizes, int n_in,
                              void* d_out, int out_size, void* d_ws, size_t ws_size,
                              hipStream_t stream) {
    const float* pos = (const float*)d_in[0];
    const float* neg = (const float*)d_in[1];
    const int* pos_classes = (const int*)d_in[2];
    const int* target_class = (const int*)d_in[3];
    const float* Wp1 = (const float*)d_in[4];
    const float* bp1 = (const float*)d_in[5];
    const float* Wp2 = (const float*)d_in[6];
    const float* bp2 = (const float*)d_in[7];
    const float* Wu1 = (const float*)d_in[8];
    const float* bu1 = (const float*)d_in[9];
    const float* Wu2 = (const float*)d_in[10];
    const float* bu2 = (const float*)d_in[11];

    float* wsf = (float*)d_ws;
    float* HU0 = wsf;                       // 1048576
    float* HP0 = HU0 + 1048576;             // 1048576
    float* HP1 = HP0 + 1048576;             // 1048576
    float* HU1n = HP1 + 1048576;            // 524288
    float* t0 = HU1n + 524288;              // 8192
    float* sc0 = t0 + 8192;                 // 524288
    float* tA = sc0 + 524288;               // 2048
    int* pA = (int*)(tA + 2048);            // 2048
    u64* g4top = (u64*)(pA + 2048);         // 64*64 u64
    float* outp = (float*)d_out;

    g1_gemm<<<452, 256, 0, stream>>>(pos, neg, Wu1, Wp1, pos_classes,
                                     target_class, HU0, HU1n, HP0, HP1, outp);
    g2_ue_sc0<<<512, 256, 0, stream>>>(HU0, HU1n, bu1, Wu2, bu2,
                                       HP0, HP1, bp1, Wp2, bp2, t0, sc0);
    g3_top0<<<32, 1024, 0, stream>>>(sc0, t0, tA, pA);
    g4a_s1<<<32, 256, 0, stream>>>(HP0, HP1, tA, pA, bp1, Wp2, bp2, g4top);
    g4b_s2<<<8, 256, 0, stream>>>(HP0, HP1, pA, g4top, bp1, Wp2, bp2, outp);
}